// Round 1
// baseline (8654.918 us; speedup 1.0000x reference)
//
#include <hip/hip_runtime.h>
#include <hip/hip_bf16.h>
#include <math.h>

// Problem constants
#define BB 256
#define AA 64
#define DIN 512
#define HH_ 1024
#define HHALF 512
#define OUTD 256
#define LL 3
// rows of the [B*A, H] activation matrix
#define ROWS (BB * AA)          // 16384
#define HN ((long)ROWS * HH_)   // 16,777,216 floats per activation buffer

// ---------------------------------------------------------------------------
// Generic tiled SGEMM: C = act(A @ B + bias), row-major, batched over gridDim.z
// BM=BN=64, BK=16, 256 threads, 4x4 per thread.
// ---------------------------------------------------------------------------
template <int ACT>  // 0 = none, 1 = exact GELU
__global__ __launch_bounds__(256) void sgemm_kernel(
    const float* __restrict__ Abase, const float* __restrict__ Bbase,
    const float* __restrict__ biasBase, float* __restrict__ Cbase,
    int M, int N, int K, int lda, int ldb, int ldc,
    long sA, long sB, long sBias, long sC)
{
    const float* A = Abase + (long)blockIdx.z * sA;
    const float* B = Bbase + (long)blockIdx.z * sB;
    const float* bias = biasBase + (long)blockIdx.z * sBias;
    float* C = Cbase + (long)blockIdx.z * sC;

    const int m0 = blockIdx.y * 64;
    const int n0 = blockIdx.x * 64;

    __shared__ float As[16][65];  // [k][m], padded
    __shared__ float Bs[16][65];  // [k][n], padded

    const int tid = threadIdx.x;
    const int tx = tid & 15;      // n group
    const int ty = tid >> 4;      // m group

    float acc[4][4] = {};

    for (int k0 = 0; k0 < K; k0 += 16) {
        // load A tile 64x16 (1024 elems, 4/thread), store transposed
#pragma unroll
        for (int t = 0; t < 4; ++t) {
            int idx = tid + t * 256;
            int r = idx >> 4, c = idx & 15;
            As[c][r] = A[(long)(m0 + r) * lda + (k0 + c)];
        }
        // load B tile 16x64 (1024 elems, 4/thread)
#pragma unroll
        for (int t = 0; t < 4; ++t) {
            int idx = tid + t * 256;
            int r = idx >> 6, c = idx & 63;
            Bs[r][c] = B[(long)(k0 + r) * ldb + (n0 + c)];
        }
        __syncthreads();
#pragma unroll
        for (int kk = 0; kk < 16; ++kk) {
            float ra[4], rb[4];
#pragma unroll
            for (int i = 0; i < 4; ++i) ra[i] = As[kk][ty * 4 + i];
#pragma unroll
            for (int j = 0; j < 4; ++j) rb[j] = Bs[kk][tx * 4 + j];
#pragma unroll
            for (int i = 0; i < 4; ++i)
#pragma unroll
                for (int j = 0; j < 4; ++j) acc[i][j] += ra[i] * rb[j];
        }
        __syncthreads();
    }

#pragma unroll
    for (int i = 0; i < 4; ++i) {
        int m = m0 + ty * 4 + i;
#pragma unroll
        for (int j = 0; j < 4; ++j) {
            int n = n0 + tx * 4 + j;
            float val = acc[i][j] + bias[n];
            if (ACT == 1) val = 0.5f * val * (1.0f + erff(val * 0.70710678118654752f));
            C[(long)m * ldc + n] = val;
        }
    }
}

// ---------------------------------------------------------------------------
// Row LayerNorm over H=1024, one block (256 threads) per row, float4 per thread
// ---------------------------------------------------------------------------
__global__ __launch_bounds__(256) void ln_kernel(
    const float* __restrict__ x, const float* __restrict__ g,
    const float* __restrict__ b, float* __restrict__ out)
{
    __shared__ float s1[256], s2[256];
    const long row = blockIdx.x;
    const int t = threadIdx.x;
    float4 v = ((const float4*)(x + row * HH_))[t];
    s1[t] = v.x + v.y + v.z + v.w;
    s2[t] = v.x * v.x + v.y * v.y + v.z * v.z + v.w * v.w;
    __syncthreads();
    for (int off = 128; off > 0; off >>= 1) {
        if (t < off) { s1[t] += s1[t + off]; s2[t] += s2[t + off]; }
        __syncthreads();
    }
    float mu = s1[0] * (1.0f / 1024.0f);
    float var = s2[0] * (1.0f / 1024.0f) - mu * mu;
    float rstd = rsqrtf(var + 1e-5f);
    float4 gv = ((const float4*)g)[t];
    float4 bv = ((const float4*)b)[t];
    float4 o;
    o.x = (v.x - mu) * rstd * gv.x + bv.x;
    o.y = (v.y - mu) * rstd * gv.y + bv.y;
    o.z = (v.z - mu) * rstd * gv.z + bv.z;
    o.w = (v.w - mu) * rstd * gv.w + bv.w;
    ((float4*)(out + row * HH_))[t] = o;
}

// ---------------------------------------------------------------------------
// scores[z] = Q_z @ K_z^T / sqrt(H); one block per batch z, 64x64 out, BK=32
// ---------------------------------------------------------------------------
__global__ __launch_bounds__(256) void scores_kernel(
    const float* __restrict__ q, const float* __restrict__ k, float* __restrict__ s)
{
    const int z = blockIdx.x;
    __shared__ float Qs[32][65];
    __shared__ float Ks[32][65];
    const int tid = threadIdx.x;
    const int tx = tid & 15, ty = tid >> 4;
    float acc[4][4] = {};

    for (int k0 = 0; k0 < HH_; k0 += 32) {
#pragma unroll
        for (int t = 0; t < 8; ++t) {
            int idx = tid + t * 256;       // 0..2047
            int r = idx >> 5, c = idx & 31;
            Qs[c][r] = q[(long)(z * 64 + r) * HH_ + k0 + c];
            Ks[c][r] = k[(long)(z * 64 + r) * HH_ + k0 + c];
        }
        __syncthreads();
#pragma unroll
        for (int kk = 0; kk < 32; ++kk) {
            float ra[4], rb[4];
#pragma unroll
            for (int i = 0; i < 4; ++i) ra[i] = Qs[kk][ty * 4 + i];
#pragma unroll
            for (int j = 0; j < 4; ++j) rb[j] = Ks[kk][tx * 4 + j];
#pragma unroll
            for (int i = 0; i < 4; ++i)
#pragma unroll
                for (int j = 0; j < 4; ++j) acc[i][j] += ra[i] * rb[j];
        }
        __syncthreads();
    }
    const float scale = 0.03125f;  // 1/sqrt(1024)
#pragma unroll
    for (int i = 0; i < 4; ++i)
#pragma unroll
        for (int j = 0; j < 4; ++j)
            s[(long)z * 4096 + (ty * 4 + i) * 64 + (tx * 4 + j)] = acc[i][j] * scale;
}

// ---------------------------------------------------------------------------
// Sinkhorn: 50 iters of row/col log-softmax normalization in LDS, then exp.
// One block of 64 threads per batch; 65-padded rows so both row and col
// passes are (at worst) 2-way bank aliased (free on CDNA4).
// ---------------------------------------------------------------------------
__global__ __launch_bounds__(64) void sinkhorn_kernel(float* __restrict__ s)
{
    const int z = blockIdx.x;
    const int lane = threadIdx.x;
    __shared__ float la[64 * 65];

    for (int r = 0; r < 64; ++r)
        la[r * 65 + lane] = s[(long)z * 4096 + r * 64 + lane];
    __syncthreads();

    for (int it = 0; it < 50; ++it) {
        // axis=2 (per-row over cols)
        float m = -INFINITY;
        for (int c = 0; c < 64; ++c) m = fmaxf(m, la[lane * 65 + c]);
        float sum = 0.0f;
        for (int c = 0; c < 64; ++c) sum += expf(la[lane * 65 + c] - m);
        float lse = m + logf(sum);
        for (int c = 0; c < 64; ++c) la[lane * 65 + c] -= lse;
        __syncthreads();
        // axis=1 (per-col over rows)
        m = -INFINITY;
        for (int r = 0; r < 64; ++r) m = fmaxf(m, la[r * 65 + lane]);
        sum = 0.0f;
        for (int r = 0; r < 64; ++r) sum += expf(la[r * 65 + lane] - m);
        lse = m + logf(sum);
        for (int r = 0; r < 64; ++r) la[r * 65 + lane] -= lse;
        __syncthreads();
    }
    for (int r = 0; r < 64; ++r)
        s[(long)z * 4096 + r * 64 + lane] = expf(la[r * 65 + lane]);
}

// ---------------------------------------------------------------------------
// attended = attn @ V per batch. grid (16 n-tiles, 256 batches), block (64,4).
// Each thread: fixed n, 16 agent rows.
// ---------------------------------------------------------------------------
__global__ __launch_bounds__(256) void attn_v_kernel(
    const float* __restrict__ attn, const float* __restrict__ v, float* __restrict__ out)
{
    const int z = blockIdx.y;
    const int n = blockIdx.x * 64 + threadIdx.x;
    __shared__ float Ss[64 * 65];
    const int tid = threadIdx.y * 64 + threadIdx.x;
#pragma unroll
    for (int t = 0; t < 16; ++t) {
        int idx = tid + t * 256;
        int r = idx >> 6, c = idx & 63;
        Ss[r * 65 + c] = attn[(long)z * 4096 + idx];
    }
    __syncthreads();

    float acc[16] = {};
    for (int c = 0; c < 64; ++c) {
        float vv = v[(long)(z * 64 + c) * HH_ + n];
#pragma unroll
        for (int ii = 0; ii < 16; ++ii)
            acc[ii] += Ss[(threadIdx.y * 16 + ii) * 65 + c] * vv;
    }
#pragma unroll
    for (int ii = 0; ii < 16; ++ii)
        out[(long)(z * 64 + threadIdx.y * 16 + ii) * HH_ + n] = acc[ii];
}

// ---------------------------------------------------------------------------
// mix = 0.1*ns + 0.9*att; scaled = (mix+ab)*sf; bounded = scaled/max(1,||scaled||);
// h += bounded; optional inter-layer LN. One block (256 thr) per row.
// ---------------------------------------------------------------------------
__global__ __launch_bounds__(256) void mix_kernel(
    const float* __restrict__ ns, const float* __restrict__ att,
    const float* __restrict__ ab, const float* __restrict__ sf,
    float* __restrict__ h,
    const float* __restrict__ ig, const float* __restrict__ ib, int doLN)
{
    __shared__ float s1[256], s2[256];
    const long row = blockIdx.x;
    const int a = (int)(row & 63);
    const int t = threadIdx.x;

    float4 nv = ((const float4*)(ns + row * HH_))[t];
    float4 av = ((const float4*)(att + row * HH_))[t];
    float4 abv = ((const float4*)(ab + (long)a * HH_))[t];
    float sfa = sf[a];

    float4 sc;
    sc.x = (0.1f * nv.x + 0.9f * av.x + abv.x) * sfa;
    sc.y = (0.1f * nv.y + 0.9f * av.y + abv.y) * sfa;
    sc.z = (0.1f * nv.z + 0.9f * av.z + abv.z) * sfa;
    sc.w = (0.1f * nv.w + 0.9f * av.w + abv.w) * sfa;

    s1[t] = sc.x * sc.x + sc.y * sc.y + sc.z * sc.z + sc.w * sc.w;
    __syncthreads();
    for (int off = 128; off > 0; off >>= 1) {
        if (t < off) s1[t] += s1[t + off];
        __syncthreads();
    }
    float norm = sqrtf(s1[0]);
    float inv = norm > 1.0f ? 1.0f / norm : 1.0f;

    float4 hv = ((const float4*)(h + row * HH_))[t];
    float4 hn;
    hn.x = hv.x + sc.x * inv;
    hn.y = hv.y + sc.y * inv;
    hn.z = hv.z + sc.z * inv;
    hn.w = hv.w + sc.w * inv;

    if (!doLN) {
        ((float4*)(h + row * HH_))[t] = hn;
        return;
    }
    __syncthreads();  // protect s1 reuse
    s1[t] = hn.x + hn.y + hn.z + hn.w;
    s2[t] = hn.x * hn.x + hn.y * hn.y + hn.z * hn.z + hn.w * hn.w;
    __syncthreads();
    for (int off = 128; off > 0; off >>= 1) {
        if (t < off) { s1[t] += s1[t + off]; s2[t] += s2[t + off]; }
        __syncthreads();
    }
    float mu = s1[0] * (1.0f / 1024.0f);
    float var = s2[0] * (1.0f / 1024.0f) - mu * mu;
    float rstd = rsqrtf(var + 1e-5f);
    float4 gv = ((const float4*)ig)[t];
    float4 bv = ((const float4*)ib)[t];
    hn.x = (hn.x - mu) * rstd * gv.x + bv.x;
    hn.y = (hn.y - mu) * rstd * gv.y + bv.y;
    hn.z = (hn.z - mu) * rstd * gv.z + bv.z;
    hn.w = (hn.w - mu) * rstd * gv.w + bv.w;
    ((float4*)(h + row * HH_))[t] = hn;
}

// ---------------------------------------------------------------------------
extern "C" void kernel_launch(void* const* d_in, const int* in_sizes, int n_in,
                              void* d_out, int out_size, void* d_ws, size_t ws_size,
                              hipStream_t stream)
{
    const float* agent_states = (const float*)d_in[0];
    const float* Win   = (const float*)d_in[1];
    const float* bin_  = (const float*)d_in[2];
    const float* ln_g  = (const float*)d_in[3];
    const float* ln_b  = (const float*)d_in[4];
    const float* Wq    = (const float*)d_in[5];
    const float* bq    = (const float*)d_in[6];
    const float* Wk    = (const float*)d_in[7];
    const float* bk    = (const float*)d_in[8];
    const float* Wv    = (const float*)d_in[9];
    const float* bv    = (const float*)d_in[10];
    const float* ab    = (const float*)d_in[11];
    const float* sf    = (const float*)d_in[12];
    const float* ilg   = (const float*)d_in[13];
    const float* ilb   = (const float*)d_in[14];
    const float* W1    = (const float*)d_in[15];
    const float* b1    = (const float*)d_in[16];
    const float* W2    = (const float*)d_in[17];
    const float* b2    = (const float*)d_in[18];
    float* out = (float*)d_out;
    float* ws  = (float*)d_ws;

    float* h  = ws;
    float* ns = ws + HN;
    float* q  = ws + 2 * HN;
    float* k  = ws + 3 * HN;
    float* v  = ws + 4 * HN;
    float* sc = ws + 5 * HN;      // 256*64*64 floats
    float* y  = ns;               // reuse ns for head intermediate (8.4M < HN)
    float* att = k;               // reuse k for attended

    // input projection: [16384,512] @ [512,1024] + bin -> h
    sgemm_kernel<0><<<dim3(HH_ / 64, ROWS / 64, 1), 256, 0, stream>>>(
        agent_states, Win, bin_, h, ROWS, HH_, DIN, DIN, HH_, HH_, 0, 0, 0, 0);

    for (int i = 0; i < LL; ++i) {
        const long wOff = (long)i * HH_ * HH_;
        ln_kernel<<<ROWS, 256, 0, stream>>>(h, ln_g + i * HH_, ln_b + i * HH_, ns);
        sgemm_kernel<0><<<dim3(HH_ / 64, ROWS / 64, 1), 256, 0, stream>>>(
            ns, Wq + wOff, bq + i * HH_, q, ROWS, HH_, HH_, HH_, HH_, HH_, 0, 0, 0, 0);
        sgemm_kernel<0><<<dim3(HH_ / 64, ROWS / 64, 1), 256, 0, stream>>>(
            ns, Wk + wOff, bk + i * HH_, k, ROWS, HH_, HH_, HH_, HH_, HH_, 0, 0, 0, 0);
        sgemm_kernel<0><<<dim3(HH_ / 64, ROWS / 64, 1), 256, 0, stream>>>(
            ns, Wv + wOff, bv + i * HH_, v, ROWS, HH_, HH_, HH_, HH_, HH_, 0, 0, 0, 0);
        scores_kernel<<<BB, 256, 0, stream>>>(q, k, sc);
        sinkhorn_kernel<<<BB, 64, 0, stream>>>(sc);
        attn_v_kernel<<<dim3(16, BB), dim3(64, 4), 0, stream>>>(sc, v, att);
        const float* igp = ilg + (i < LL - 1 ? i : 0) * HH_;
        const float* ibp = ilb + (i < LL - 1 ? i : 0) * HH_;
        mix_kernel<<<ROWS, 256, 0, stream>>>(
            ns, att, ab + (long)i * AA * HH_, sf + i * AA, h, igp, ibp, (i < LL - 1) ? 1 : 0);
    }

    // heads: y = gelu(h_a @ W1[a] + b1[a]); out = y @ W2[a] + b2[a]
    sgemm_kernel<1><<<dim3(HHALF / 64, BB / 64, AA), 256, 0, stream>>>(
        h, W1, b1, y, BB, HHALF, HH_,
        /*lda*/ AA * HH_, /*ldb*/ HHALF, /*ldc*/ AA * HHALF,
        /*sA*/ HH_, /*sB*/ (long)HH_ * HHALF, /*sBias*/ HHALF, /*sC*/ HHALF);
    sgemm_kernel<0><<<dim3(OUTD / 64, BB / 64, AA), 256, 0, stream>>>(
        y, W2, b2, out, BB, OUTD, HHALF,
        /*lda*/ AA * HHALF, /*ldb*/ OUTD, /*ldc*/ AA * OUTD,
        /*sA*/ HHALF, /*sB*/ (long)HHALF * OUTD, /*sBias*/ OUTD, /*sC*/ OUTD);
}

// Round 2
// 1739.585 us; speedup vs baseline: 4.9753x; 4.9753x over previous
//
#include <hip/hip_runtime.h>
#include <hip/hip_bf16.h>
#include <math.h>

// Problem constants
#define BB 256
#define AA 64
#define DIN 512
#define HH_ 1024
#define HHALF 512
#define OUTD 256
#define LL 3
#define ROWS (BB * AA)          // 16384
#define HN ((long)ROWS * HH_)   // 16,777,216 elements per activation buffer

typedef float f32x4 __attribute__((ext_vector_type(4)));
typedef __bf16 bf16x8 __attribute__((ext_vector_type(8)));
typedef __bf16 bf16x4 __attribute__((ext_vector_type(4)));

__device__ __forceinline__ void gld_lds16(const void* g, void* l) {
    __builtin_amdgcn_global_load_lds(
        (const __attribute__((address_space(1))) unsigned int*)g,
        (__attribute__((address_space(3))) unsigned int*)l, 16, 0, 0);
}

// ---------------------------------------------------------------------------
// bf16 MFMA GEMM (m97 structure): C = act(A @ Bt^T + bias)
// A: [M][K] bf16 row-major (lda). Bt: [N][K] bf16 row-major (ldb) = B transposed.
// 128x128 tile, BK=32, 256 thr = 4 waves, each wave 64x64 via 4x4 16x16x32 MFMA.
// Batched over blockIdx.z with element strides sA/sB/sBias/sC.
// ---------------------------------------------------------------------------
#define TK 32
template <int ACT, int OUT_BF16>  // ACT: 1 = exact GELU
__global__ __launch_bounds__(256) void mfma_gemm(
    const __bf16* __restrict__ Abase, const __bf16* __restrict__ Btbase,
    const float* __restrict__ biasBase, float* __restrict__ Cf,
    __bf16* __restrict__ Cb,
    int M, int N, int K, int lda, int ldb, int ldc,
    long sA, long sB, long sBias, long sC)
{
    const int z = blockIdx.z;
    const __bf16* A  = Abase  + (long)z * sA;
    const __bf16* Bt = Btbase + (long)z * sB;
    const float* bias = biasBase + (long)z * sBias;

    const int m0 = blockIdx.y * 128;
    const int n0 = blockIdx.x * 128;

    __shared__ __bf16 sAt[128 * TK];   // [m][k]
    __shared__ __bf16 sBt[128 * TK];   // [n][k]

    const int t    = threadIdx.x;
    const int wv   = t >> 6;
    const int lane = t & 63;
    const int quad = lane >> 4;
    const int lrow = lane & 15;
    const int wm = (wv >> 1) * 64;
    const int wn = (wv & 1) * 64;

    f32x4 acc[4][4] = {};

    // staging map: thread t loads 16B = 8 bf16; row = t>>2, k-off = (t&3)*8
    const int sr = t >> 2;
    const int sk = (t & 3) * 8;
    // wave-uniform LDS bases (each wave covers 512 elements = 1024B per pass)
    __bf16* la0 = sAt + wv * 512;
    __bf16* la1 = sAt + 64 * TK + wv * 512;
    __bf16* lb0 = sBt + wv * 512;
    __bf16* lb1 = sBt + 64 * TK + wv * 512;

    for (int k0 = 0; k0 < K; k0 += TK) {
        gld_lds16(A  + (long)(m0 + sr)      * lda + k0 + sk, la0);
        gld_lds16(A  + (long)(m0 + 64 + sr) * lda + k0 + sk, la1);
        gld_lds16(Bt + (long)(n0 + sr)      * ldb + k0 + sk, lb0);
        gld_lds16(Bt + (long)(n0 + 64 + sr) * ldb + k0 + sk, lb1);
        __syncthreads();

        bf16x8 af[4], bfr[4];
#pragma unroll
        for (int i = 0; i < 4; ++i)
            af[i] = *(const bf16x8*)(sAt + (wm + i * 16 + lrow) * TK + quad * 8);
#pragma unroll
        for (int j = 0; j < 4; ++j)
            bfr[j] = *(const bf16x8*)(sBt + (wn + j * 16 + lrow) * TK + quad * 8);
#pragma unroll
        for (int i = 0; i < 4; ++i)
#pragma unroll
            for (int j = 0; j < 4; ++j)
                acc[i][j] = __builtin_amdgcn_mfma_f32_16x16x32_bf16(
                    af[i], bfr[j], acc[i][j], 0, 0, 0);
        __syncthreads();
    }

#pragma unroll
    for (int i = 0; i < 4; ++i) {
#pragma unroll
        for (int p = 0; p < 4; ++p) {
            const int m = m0 + wm + i * 16 + quad * 4 + p;
#pragma unroll
            for (int j = 0; j < 4; ++j) {
                const int n = n0 + wn + j * 16 + lrow;
                float val = acc[i][j][p] + bias[n];
                if (ACT == 1) val = 0.5f * val * (1.0f + erff(val * 0.70710678118654752f));
                if (OUT_BF16) Cb[(long)z * sC + (long)m * ldc + n] = (__bf16)val;
                else          Cf[(long)z * sC + (long)m * ldc + n] = val;
            }
        }
    }
}

// ---------------------------------------------------------------------------
// fp32 -> bf16 flat cast, 4 elems/thread (n must be multiple of 1024)
// ---------------------------------------------------------------------------
__global__ __launch_bounds__(256) void cast_kernel(
    const float* __restrict__ in, __bf16* __restrict__ out)
{
    long i = ((long)blockIdx.x * 256 + threadIdx.x) * 4;
    float4 v = *(const float4*)(in + i);
    bf16x4 o = {(__bf16)v.x, (__bf16)v.y, (__bf16)v.z, (__bf16)v.w};
    *(bf16x4*)(out + i) = o;
}

// ---------------------------------------------------------------------------
// Transpose + cast: in fp32 [R][C] -> out bf16 [C][R], batched over z.
// grid (C/32, R/32, batch), block 256 (32x8).
// ---------------------------------------------------------------------------
__global__ __launch_bounds__(256) void transpose_cast_kernel(
    const float* __restrict__ in, __bf16* __restrict__ out,
    int R, int C, long sIn, long sOut)
{
    const float* src = in + (long)blockIdx.z * sIn;
    __bf16* dst = out + (long)blockIdx.z * sOut;
    __shared__ float tile[32][33];
    const int r0 = blockIdx.y * 32, c0 = blockIdx.x * 32;
    const int tx = threadIdx.x & 31, ty = threadIdx.x >> 5;
#pragma unroll
    for (int i = 0; i < 32; i += 8)
        tile[ty + i][tx] = src[(long)(r0 + ty + i) * C + c0 + tx];
    __syncthreads();
#pragma unroll
    for (int i = 0; i < 32; i += 8)
        dst[(long)(c0 + ty + i) * R + r0 + tx] = (__bf16)tile[tx][ty + i];
}

// ---------------------------------------------------------------------------
// Row LayerNorm over H=1024; writes fp32 and bf16 copies.
// ---------------------------------------------------------------------------
__global__ __launch_bounds__(256) void ln_kernel(
    const float* __restrict__ x, const float* __restrict__ g,
    const float* __restrict__ b, float* __restrict__ out, __bf16* __restrict__ outb)
{
    __shared__ float s1[256], s2[256];
    const long row = blockIdx.x;
    const int t = threadIdx.x;
    float4 v = ((const float4*)(x + row * HH_))[t];
    s1[t] = v.x + v.y + v.z + v.w;
    s2[t] = v.x * v.x + v.y * v.y + v.z * v.z + v.w * v.w;
    __syncthreads();
    for (int off = 128; off > 0; off >>= 1) {
        if (t < off) { s1[t] += s1[t + off]; s2[t] += s2[t + off]; }
        __syncthreads();
    }
    float mu = s1[0] * (1.0f / 1024.0f);
    float var = s2[0] * (1.0f / 1024.0f) - mu * mu;
    float rstd = rsqrtf(var + 1e-5f);
    float4 gv = ((const float4*)g)[t];
    float4 bv = ((const float4*)b)[t];
    float4 o;
    o.x = (v.x - mu) * rstd * gv.x + bv.x;
    o.y = (v.y - mu) * rstd * gv.y + bv.y;
    o.z = (v.z - mu) * rstd * gv.z + bv.z;
    o.w = (v.w - mu) * rstd * gv.w + bv.w;
    ((float4*)(out + row * HH_))[t] = o;
    bf16x4 ob = {(__bf16)o.x, (__bf16)o.y, (__bf16)o.z, (__bf16)o.w};
    ((bf16x4*)(outb + row * HH_))[t] = ob;
}

// ---------------------------------------------------------------------------
// scores[z] = Q_z @ K_z^T / sqrt(H), bf16 inputs, fp32 math.
// ---------------------------------------------------------------------------
__global__ __launch_bounds__(256) void scores_kernel(
    const __bf16* __restrict__ q, const __bf16* __restrict__ k, float* __restrict__ s)
{
    const int z = blockIdx.x;
    __shared__ float Qs[32][65];
    __shared__ float Ks[32][65];
    const int tid = threadIdx.x;
    const int tx = tid & 15, ty = tid >> 4;
    float acc[4][4] = {};

    for (int k0 = 0; k0 < HH_; k0 += 32) {
#pragma unroll
        for (int t = 0; t < 8; ++t) {
            int idx = tid + t * 256;
            int r = idx >> 5, c = idx & 31;
            Qs[c][r] = (float)q[(long)(z * 64 + r) * HH_ + k0 + c];
            Ks[c][r] = (float)k[(long)(z * 64 + r) * HH_ + k0 + c];
        }
        __syncthreads();
#pragma unroll
        for (int kk = 0; kk < 32; ++kk) {
            float ra[4], rb[4];
#pragma unroll
            for (int i = 0; i < 4; ++i) ra[i] = Qs[kk][ty * 4 + i];
#pragma unroll
            for (int j = 0; j < 4; ++j) rb[j] = Ks[kk][tx * 4 + j];
#pragma unroll
            for (int i = 0; i < 4; ++i)
#pragma unroll
                for (int j = 0; j < 4; ++j) acc[i][j] += ra[i] * rb[j];
        }
        __syncthreads();
    }
    const float scale = 0.03125f;
#pragma unroll
    for (int i = 0; i < 4; ++i)
#pragma unroll
        for (int j = 0; j < 4; ++j)
            s[(long)z * 4096 + (ty * 4 + i) * 64 + (tx * 4 + j)] = acc[i][j] * scale;
}

// ---------------------------------------------------------------------------
// Sinkhorn: 256 threads/block. Wave w handles a 16-wide slice; rows/cols in regs.
// ---------------------------------------------------------------------------
__global__ __launch_bounds__(256) void sinkhorn_kernel(float* __restrict__ s)
{
    const int z = blockIdx.x;
    const int t = threadIdx.x;
    const int lane = t & 63;
    const int w = t >> 6;
    __shared__ float la[64 * 65];
    __shared__ float pm[4][64], ps[4][64];

    const float4* src = (const float4*)(s + (long)z * 4096);
#pragma unroll
    for (int i = 0; i < 4; ++i) {
        int idx = t + i * 256;
        float4 vv = src[idx];
        int r = idx >> 4, c = (idx & 15) * 4;
        la[r * 65 + c]     = vv.x;
        la[r * 65 + c + 1] = vv.y;
        la[r * 65 + c + 2] = vv.z;
        la[r * 65 + c + 3] = vv.w;
    }
    __syncthreads();

    for (int it = 0; it < 50; ++it) {
        // row phase: row=lane, cols w*16..+15
        {
            float vr[16];
            float m = -INFINITY;
#pragma unroll
            for (int i = 0; i < 16; ++i) { vr[i] = la[lane * 65 + w * 16 + i]; m = fmaxf(m, vr[i]); }
            float sum = 0.f;
#pragma unroll
            for (int i = 0; i < 16; ++i) sum += __expf(vr[i] - m);
            pm[w][lane] = m; ps[w][lane] = sum;
            __syncthreads();
            float m0 = pm[0][lane], m1 = pm[1][lane], m2 = pm[2][lane], m3 = pm[3][lane];
            float M = fmaxf(fmaxf(m0, m1), fmaxf(m2, m3));
            float S = ps[0][lane] * __expf(m0 - M) + ps[1][lane] * __expf(m1 - M)
                    + ps[2][lane] * __expf(m2 - M) + ps[3][lane] * __expf(m3 - M);
            float lse = M + __logf(S);
#pragma unroll
            for (int i = 0; i < 16; ++i) la[lane * 65 + w * 16 + i] = vr[i] - lse;
            __syncthreads();
        }
        // col phase: col=lane, rows w*16..+15
        {
            float vr[16];
            float m = -INFINITY;
#pragma unroll
            for (int i = 0; i < 16; ++i) { vr[i] = la[(w * 16 + i) * 65 + lane]; m = fmaxf(m, vr[i]); }
            float sum = 0.f;
#pragma unroll
            for (int i = 0; i < 16; ++i) sum += __expf(vr[i] - m);
            pm[w][lane] = m; ps[w][lane] = sum;
            __syncthreads();
            float m0 = pm[0][lane], m1 = pm[1][lane], m2 = pm[2][lane], m3 = pm[3][lane];
            float M = fmaxf(fmaxf(m0, m1), fmaxf(m2, m3));
            float S = ps[0][lane] * __expf(m0 - M) + ps[1][lane] * __expf(m1 - M)
                    + ps[2][lane] * __expf(m2 - M) + ps[3][lane] * __expf(m3 - M);
            float lse = M + __logf(S);
#pragma unroll
            for (int i = 0; i < 16; ++i) la[(w * 16 + i) * 65 + lane] = vr[i] - lse;
            __syncthreads();
        }
    }
#pragma unroll
    for (int i = 0; i < 4; ++i) {
        int idx = t + i * 256;
        int r = idx >> 4, c = (idx & 15) * 4;
        float4 o;
        o.x = __expf(la[r * 65 + c]);
        o.y = __expf(la[r * 65 + c + 1]);
        o.z = __expf(la[r * 65 + c + 2]);
        o.w = __expf(la[r * 65 + c + 3]);
        ((float4*)(s + (long)z * 4096))[idx] = o;
    }
}

// ---------------------------------------------------------------------------
// attended = attn @ V per batch (attn fp32, V bf16, out fp32)
// ---------------------------------------------------------------------------
__global__ __launch_bounds__(256) void attn_v_kernel(
    const float* __restrict__ attn, const __bf16* __restrict__ v, float* __restrict__ out)
{
    const int z = blockIdx.y;
    const int n = blockIdx.x * 64 + threadIdx.x;
    __shared__ float Ss[64 * 65];
    const int tid = threadIdx.y * 64 + threadIdx.x;
#pragma unroll
    for (int t = 0; t < 16; ++t) {
        int idx = tid + t * 256;
        int r = idx >> 6, c = idx & 63;
        Ss[r * 65 + c] = attn[(long)z * 4096 + idx];
    }
    __syncthreads();

    float acc[16] = {};
    for (int c = 0; c < 64; ++c) {
        float vv = (float)v[(long)(z * 64 + c) * HH_ + n];
#pragma unroll
        for (int ii = 0; ii < 16; ++ii)
            acc[ii] += Ss[(threadIdx.y * 16 + ii) * 65 + c] * vv;
    }
#pragma unroll
    for (int ii = 0; ii < 16; ++ii)
        out[(long)(z * 64 + threadIdx.y * 16 + ii) * HH_ + n] = acc[ii];
}

// ---------------------------------------------------------------------------
// mix + signal-bound + residual (+ optional inter-LN) (+ optional bf16 h copy)
// ---------------------------------------------------------------------------
__global__ __launch_bounds__(256) void mix_kernel(
    const float* __restrict__ ns, const float* __restrict__ att,
    const float* __restrict__ ab, const float* __restrict__ sf,
    float* __restrict__ h,
    const float* __restrict__ ig, const float* __restrict__ ib, int doLN,
    __bf16* __restrict__ hbf)
{
    __shared__ float s1[256], s2[256];
    const long row = blockIdx.x;
    const int a = (int)(row & 63);
    const int t = threadIdx.x;

    float4 nv = ((const float4*)(ns + row * HH_))[t];
    float4 av = ((const float4*)(att + row * HH_))[t];
    float4 abv = ((const float4*)(ab + (long)a * HH_))[t];
    float sfa = sf[a];

    float4 sc;
    sc.x = (0.1f * nv.x + 0.9f * av.x + abv.x) * sfa;
    sc.y = (0.1f * nv.y + 0.9f * av.y + abv.y) * sfa;
    sc.z = (0.1f * nv.z + 0.9f * av.z + abv.z) * sfa;
    sc.w = (0.1f * nv.w + 0.9f * av.w + abv.w) * sfa;

    s1[t] = sc.x * sc.x + sc.y * sc.y + sc.z * sc.z + sc.w * sc.w;
    __syncthreads();
    for (int off = 128; off > 0; off >>= 1) {
        if (t < off) s1[t] += s1[t + off];
        __syncthreads();
    }
    float norm = sqrtf(s1[0]);
    float inv = norm > 1.0f ? 1.0f / norm : 1.0f;

    float4 hv = ((const float4*)(h + row * HH_))[t];
    float4 hn;
    hn.x = hv.x + sc.x * inv;
    hn.y = hv.y + sc.y * inv;
    hn.z = hv.z + sc.z * inv;
    hn.w = hv.w + sc.w * inv;

    if (!doLN) {
        ((float4*)(h + row * HH_))[t] = hn;
        if (hbf) {
            bf16x4 ob = {(__bf16)hn.x, (__bf16)hn.y, (__bf16)hn.z, (__bf16)hn.w};
            ((bf16x4*)(hbf + row * HH_))[t] = ob;
        }
        return;
    }
    __syncthreads();
    s1[t] = hn.x + hn.y + hn.z + hn.w;
    s2[t] = hn.x * hn.x + hn.y * hn.y + hn.z * hn.z + hn.w * hn.w;
    __syncthreads();
    for (int off = 128; off > 0; off >>= 1) {
        if (t < off) { s1[t] += s1[t + off]; s2[t] += s2[t + off]; }
        __syncthreads();
    }
    float mu = s1[0] * (1.0f / 1024.0f);
    float var = s2[0] * (1.0f / 1024.0f) - mu * mu;
    float rstd = rsqrtf(var + 1e-5f);
    float4 gv = ((const float4*)ig)[t];
    float4 bv = ((const float4*)ib)[t];
    hn.x = (hn.x - mu) * rstd * gv.x + bv.x;
    hn.y = (hn.y - mu) * rstd * gv.y + bv.y;
    hn.z = (hn.z - mu) * rstd * gv.z + bv.z;
    hn.w = (hn.w - mu) * rstd * gv.w + bv.w;
    ((float4*)(h + row * HH_))[t] = hn;
}

// ---------------------------------------------------------------------------
extern "C" void kernel_launch(void* const* d_in, const int* in_sizes, int n_in,
                              void* d_out, int out_size, void* d_ws, size_t ws_size,
                              hipStream_t stream)
{
    const float* agent_states = (const float*)d_in[0];
    const float* Win   = (const float*)d_in[1];
    const float* bin_  = (const float*)d_in[2];
    const float* ln_g  = (const float*)d_in[3];
    const float* ln_b  = (const float*)d_in[4];
    const float* Wq    = (const float*)d_in[5];
    const float* bq    = (const float*)d_in[6];
    const float* Wk    = (const float*)d_in[7];
    const float* bk    = (const float*)d_in[8];
    const float* Wv    = (const float*)d_in[9];
    const float* bv    = (const float*)d_in[10];
    const float* ab    = (const float*)d_in[11];
    const float* sf    = (const float*)d_in[12];
    const float* ilg   = (const float*)d_in[13];
    const float* ilb   = (const float*)d_in[14];
    const float* W1    = (const float*)d_in[15];
    const float* b1    = (const float*)d_in[16];
    const float* W2    = (const float*)d_in[17];
    const float* b2    = (const float*)d_in[18];
    float* out = (float*)d_out;

    // ---- workspace layout ----
    float* ws_f = (float*)d_ws;
    float* h   = ws_f;               // HN
    float* ns  = ws_f + HN;          // HN (later overlaid by W1t)
    float* att = ws_f + 2 * HN;      // HN (early: asb+Wint; late: W2t+yb)
    float* sc  = ws_f + 3 * HN;      // 1M floats

    __bf16* bfb = (__bf16*)((char*)d_ws + (3 * HN + 1048576) * sizeof(float));
    __bf16* nsb = bfb;               // HN
    __bf16* qb  = nsb + HN;          // HN
    __bf16* kb  = qb + HN;           // HN
    __bf16* vb  = kb + HN;           // HN
    __bf16* hb  = vb + HN;           // HN
    __bf16* Wqt = hb + HN;           // 3*1024*1024
    __bf16* Wkt = Wqt + 3 * 1024 * 1024;
    __bf16* Wvt = Wkt + 3 * 1024 * 1024;
    // overlays (time-disjoint with their fp32 hosts)
    __bf16* asb  = (__bf16*)att;                 // 8.4M elems, pre-loop only
    __bf16* Wint = asb + 8388608;                // 0.5M elems, pre-loop only
    __bf16* W1t  = (__bf16*)ns;                  // 33.5M elems, post-loop only
    __bf16* W2t  = (__bf16*)att;                 // 8.4M elems, post-loop only
    __bf16* yb   = (__bf16*)att + 16777216;      // 8.4M elems, post-loop only

    // ---- pre: casts & weight transposes ----
    cast_kernel<<<8192, 256, 0, stream>>>(agent_states, asb);   // 8,388,608 elems
    transpose_cast_kernel<<<dim3(32, 16, 1), 256, 0, stream>>>(Win, Wint, 512, 1024, 0, 0);
    transpose_cast_kernel<<<dim3(32, 32, 3), 256, 0, stream>>>(Wq, Wqt, 1024, 1024,
                                                               1048576, 1048576);
    transpose_cast_kernel<<<dim3(32, 32, 3), 256, 0, stream>>>(Wk, Wkt, 1024, 1024,
                                                               1048576, 1048576);
    transpose_cast_kernel<<<dim3(32, 32, 3), 256, 0, stream>>>(Wv, Wvt, 1024, 1024,
                                                               1048576, 1048576);

    // ---- input projection: h = asb @ Win + bin ----
    mfma_gemm<0, 0><<<dim3(8, 128, 1), 256, 0, stream>>>(
        asb, Wint, bin_, h, nullptr, ROWS, HH_, DIN, DIN, DIN, HH_, 0, 0, 0, 0);

    for (int i = 0; i < LL; ++i) {
        const long wOff = (long)i * HH_ * HH_;
        ln_kernel<<<ROWS, 256, 0, stream>>>(h, ln_g + i * HH_, ln_b + i * HH_, ns, nsb);
        mfma_gemm<0, 1><<<dim3(8, 128, 1), 256, 0, stream>>>(
            nsb, Wqt + wOff, bq + i * HH_, nullptr, qb,
            ROWS, HH_, HH_, HH_, HH_, HH_, 0, 0, 0, 0);
        mfma_gemm<0, 1><<<dim3(8, 128, 1), 256, 0, stream>>>(
            nsb, Wkt + wOff, bk + i * HH_, nullptr, kb,
            ROWS, HH_, HH_, HH_, HH_, HH_, 0, 0, 0, 0);
        mfma_gemm<0, 1><<<dim3(8, 128, 1), 256, 0, stream>>>(
            nsb, Wvt + wOff, bv + i * HH_, nullptr, vb,
            ROWS, HH_, HH_, HH_, HH_, HH_, 0, 0, 0, 0);
        scores_kernel<<<BB, 256, 0, stream>>>(qb, kb, sc);
        sinkhorn_kernel<<<BB, 256, 0, stream>>>(sc);
        attn_v_kernel<<<dim3(16, BB), dim3(64, 4), 0, stream>>>(sc, vb, att);
        const float* igp = ilg + (i < LL - 1 ? i : 0) * HH_;
        const float* ibp = ilb + (i < LL - 1 ? i : 0) * HH_;
        mix_kernel<<<ROWS, 256, 0, stream>>>(
            ns, att, ab + (long)i * AA * HH_, sf + i * AA, h, igp, ibp,
            (i < LL - 1) ? 1 : 0, (i == LL - 1) ? hb : nullptr);
    }

    // ---- heads ----
    transpose_cast_kernel<<<dim3(16, 32, 64), 256, 0, stream>>>(W1, W1t, 1024, 512,
                                                                524288, 524288);
    transpose_cast_kernel<<<dim3(8, 16, 64), 256, 0, stream>>>(W2, W2t, 512, 256,
                                                               131072, 131072);
    // y = gelu(h_a @ W1[a] + b1[a])  (bf16 out)
    mfma_gemm<1, 1><<<dim3(4, 2, 64), 256, 0, stream>>>(
        hb, W1t, b1, nullptr, yb, BB, HHALF, HH_,
        /*lda*/ AA * HH_, /*ldb*/ HH_, /*ldc*/ AA * HHALF,
        /*sA*/ HH_, /*sB*/ (long)HHALF * HH_, /*sBias*/ HHALF, /*sC*/ HHALF);
    // out = y @ W2[a] + b2[a]  (fp32 out)
    mfma_gemm<0, 0><<<dim3(2, 2, 64), 256, 0, stream>>>(
        yb, W2t, b2, out, nullptr, BB, OUTD, HHALF,
        /*lda*/ AA * HHALF, /*ldb*/ HHALF, /*ldc*/ AA * OUTD,
        /*sA*/ HHALF, /*sB*/ (long)OUTD * HHALF, /*sBias*/ OUTD, /*sC*/ OUTD);
}

// Round 3
// 1401.110 us; speedup vs baseline: 6.1772x; 1.2416x over previous
//
#include <hip/hip_runtime.h>
#include <hip/hip_bf16.h>
#include <math.h>

// Problem constants
#define BB 256
#define AA 64
#define DIN 512
#define HH_ 1024
#define HHALF 512
#define OUTD 256
#define LL 3
#define ROWS (BB * AA)          // 16384
#define HN ((long)ROWS * HH_)   // 16,777,216 elements per activation buffer

typedef float f32x4 __attribute__((ext_vector_type(4)));
typedef __bf16 bf16x8 __attribute__((ext_vector_type(8)));
typedef __bf16 bf16x4 __attribute__((ext_vector_type(4)));

__device__ __forceinline__ void gld_lds16(const void* g, void* l) {
    __builtin_amdgcn_global_load_lds(
        (const __attribute__((address_space(1))) unsigned int*)g,
        (__attribute__((address_space(3))) unsigned int*)l, 16, 0, 0);
}

// ---------------------------------------------------------------------------
// bf16 MFMA GEMM (m97 structure): C = act(A @ Bt^T + bias)
// A: [M][K] bf16 (lda). Bt: [N][K] bf16 (ldb). 128x128 tile, BK=32,
// 256 thr = 4 waves, each wave 64x64 via 4x4 16x16x32 MFMA. Batched over z.
// ---------------------------------------------------------------------------
#define TK 32
template <int ACT, int OUT_BF16>  // ACT: 1 = exact GELU
__global__ __launch_bounds__(256) void mfma_gemm(
    const __bf16* __restrict__ Abase, const __bf16* __restrict__ Btbase,
    const float* __restrict__ biasBase, float* __restrict__ Cf,
    __bf16* __restrict__ Cb,
    int M, int N, int K, int lda, int ldb, int ldc,
    long sA, long sB, long sBias, long sC)
{
    const int z = blockIdx.z;
    const __bf16* A  = Abase  + (long)z * sA;
    const __bf16* Bt = Btbase + (long)z * sB;
    const float* bias = biasBase + (long)z * sBias;

    const int m0 = blockIdx.y * 128;
    const int n0 = blockIdx.x * 128;

    __shared__ __bf16 sAt[128 * TK];   // [m][k]
    __shared__ __bf16 sBt[128 * TK];   // [n][k]

    const int t    = threadIdx.x;
    const int wv   = t >> 6;
    const int lane = t & 63;
    const int quad = lane >> 4;
    const int lrow = lane & 15;
    const int wm = (wv >> 1) * 64;
    const int wn = (wv & 1) * 64;

    f32x4 acc[4][4] = {};

    const int sr = t >> 2;
    const int sk = (t & 3) * 8;
    __bf16* la0 = sAt + wv * 512;
    __bf16* la1 = sAt + 64 * TK + wv * 512;
    __bf16* lb0 = sBt + wv * 512;
    __bf16* lb1 = sBt + 64 * TK + wv * 512;

    for (int k0 = 0; k0 < K; k0 += TK) {
        gld_lds16(A  + (long)(m0 + sr)      * lda + k0 + sk, la0);
        gld_lds16(A  + (long)(m0 + 64 + sr) * lda + k0 + sk, la1);
        gld_lds16(Bt + (long)(n0 + sr)      * ldb + k0 + sk, lb0);
        gld_lds16(Bt + (long)(n0 + 64 + sr) * ldb + k0 + sk, lb1);
        __syncthreads();

        bf16x8 af[4], bfr[4];
#pragma unroll
        for (int i = 0; i < 4; ++i)
            af[i] = *(const bf16x8*)(sAt + (wm + i * 16 + lrow) * TK + quad * 8);
#pragma unroll
        for (int j = 0; j < 4; ++j)
            bfr[j] = *(const bf16x8*)(sBt + (wn + j * 16 + lrow) * TK + quad * 8);
#pragma unroll
        for (int i = 0; i < 4; ++i)
#pragma unroll
            for (int j = 0; j < 4; ++j)
                acc[i][j] = __builtin_amdgcn_mfma_f32_16x16x32_bf16(
                    af[i], bfr[j], acc[i][j], 0, 0, 0);
        __syncthreads();
    }

#pragma unroll
    for (int i = 0; i < 4; ++i) {
#pragma unroll
        for (int p = 0; p < 4; ++p) {
            const int m = m0 + wm + i * 16 + quad * 4 + p;
#pragma unroll
            for (int j = 0; j < 4; ++j) {
                const int n = n0 + wn + j * 16 + lrow;
                float val = acc[i][j][p] + bias[n];
                if (ACT == 1) val = 0.5f * val * (1.0f + erff(val * 0.70710678118654752f));
                if (OUT_BF16) Cb[(long)z * sC + (long)m * ldc + n] = (__bf16)val;
                else          Cf[(long)z * sC + (long)m * ldc + n] = val;
            }
        }
    }
}

// ---------------------------------------------------------------------------
// fp32 -> bf16 flat cast
// ---------------------------------------------------------------------------
__global__ __launch_bounds__(256) void cast_kernel(
    const float* __restrict__ in, __bf16* __restrict__ out)
{
    long i = ((long)blockIdx.x * 256 + threadIdx.x) * 4;
    float4 v = *(const float4*)(in + i);
    bf16x4 o = {(__bf16)v.x, (__bf16)v.y, (__bf16)v.z, (__bf16)v.w};
    *(bf16x4*)(out + i) = o;
}

// ---------------------------------------------------------------------------
// Transpose + cast: fp32 [R][C] -> bf16 [C][R], batched over z.
// ---------------------------------------------------------------------------
__global__ __launch_bounds__(256) void transpose_cast_kernel(
    const float* __restrict__ in, __bf16* __restrict__ out,
    int R, int C, long sIn, long sOut)
{
    const float* src = in + (long)blockIdx.z * sIn;
    __bf16* dst = out + (long)blockIdx.z * sOut;
    __shared__ float tile[32][33];
    const int r0 = blockIdx.y * 32, c0 = blockIdx.x * 32;
    const int tx = threadIdx.x & 31, ty = threadIdx.x >> 5;
#pragma unroll
    for (int i = 0; i < 32; i += 8)
        tile[ty + i][tx] = src[(long)(r0 + ty + i) * C + c0 + tx];
    __syncthreads();
#pragma unroll
    for (int i = 0; i < 32; i += 8)
        dst[(long)(c0 + ty + i) * R + r0 + tx] = (__bf16)tile[tx][ty + i];
}

// ---------------------------------------------------------------------------
// Concatenate bq|bk|bv per layer into [L][3072]
// ---------------------------------------------------------------------------
__global__ __launch_bounds__(256) void qkv_bias_kernel(
    const float* __restrict__ bq, const float* __restrict__ bk,
    const float* __restrict__ bv, float* __restrict__ ob)
{
    int i = blockIdx.x * 256 + threadIdx.x;
    if (i >= LL * 3072) return;
    int l = i / 3072, j = i - l * 3072;
    float v = (j < 1024) ? bq[l * 1024 + j]
            : (j < 2048) ? bk[l * 1024 + j - 1024]
                         : bv[l * 1024 + j - 2048];
    ob[i] = v;
}

// ---------------------------------------------------------------------------
// Row LayerNorm over H=1024 -> bf16 out only
// ---------------------------------------------------------------------------
__global__ __launch_bounds__(256) void ln_kernel(
    const float* __restrict__ x, const float* __restrict__ g,
    const float* __restrict__ b, __bf16* __restrict__ outb)
{
    __shared__ float s1[256], s2[256];
    const long row = blockIdx.x;
    const int t = threadIdx.x;
    float4 v = ((const float4*)(x + row * HH_))[t];
    s1[t] = v.x + v.y + v.z + v.w;
    s2[t] = v.x * v.x + v.y * v.y + v.z * v.z + v.w * v.w;
    __syncthreads();
    for (int off = 128; off > 0; off >>= 1) {
        if (t < off) { s1[t] += s1[t + off]; s2[t] += s2[t + off]; }
        __syncthreads();
    }
    float mu = s1[0] * (1.0f / 1024.0f);
    float var = s2[0] * (1.0f / 1024.0f) - mu * mu;
    float rstd = rsqrtf(var + 1e-5f);
    float4 gv = ((const float4*)g)[t];
    float4 bv = ((const float4*)b)[t];
    bf16x4 ob = {(__bf16)((v.x - mu) * rstd * gv.x + bv.x),
                 (__bf16)((v.y - mu) * rstd * gv.y + bv.y),
                 (__bf16)((v.z - mu) * rstd * gv.z + bv.z),
                 (__bf16)((v.w - mu) * rstd * gv.w + bv.w)};
    ((bf16x4*)(outb + row * HH_))[t] = ob;
}

// ---------------------------------------------------------------------------
// MFMA scores: s[z] = Q_z @ K_z^T / 32, Q/K = qkv rows (stride 3072),
// one block (4 waves) per z; wave = 32x32 quadrant, BK=32.
// ---------------------------------------------------------------------------
__global__ __launch_bounds__(256) void scores_mfma_kernel(
    const __bf16* __restrict__ qkv, float* __restrict__ s)
{
    const int z = blockIdx.x;
    __shared__ __bf16 sQ[64 * 32];
    __shared__ __bf16 sK[64 * 32];
    const int t = threadIdx.x;
    const int wv = t >> 6, lane = t & 63;
    const int quad = lane >> 4, lrow = lane & 15;
    const int wm = (wv >> 1) * 32, wn = (wv & 1) * 32;

    const int srow = t >> 2;            // 256 chunks of 16B, 4 per row
    const int skoff = (t & 3) * 8;
    __bf16* lq = sQ + wv * 512;
    __bf16* lk = sK + wv * 512;
    const __bf16* Q = qkv + (long)z * 64 * 3072;
    const __bf16* K = Q + 1024;

    f32x4 acc[2][2] = {};

    for (int k0 = 0; k0 < 1024; k0 += 32) {
        gld_lds16(Q + (long)srow * 3072 + k0 + skoff, lq);
        gld_lds16(K + (long)srow * 3072 + k0 + skoff, lk);
        __syncthreads();
        bf16x8 af[2], bfr[2];
#pragma unroll
        for (int i = 0; i < 2; ++i)
            af[i] = *(const bf16x8*)(sQ + (wm + i * 16 + lrow) * 32 + quad * 8);
#pragma unroll
        for (int j = 0; j < 2; ++j)
            bfr[j] = *(const bf16x8*)(sK + (wn + j * 16 + lrow) * 32 + quad * 8);
#pragma unroll
        for (int i = 0; i < 2; ++i)
#pragma unroll
            for (int j = 0; j < 2; ++j)
                acc[i][j] = __builtin_amdgcn_mfma_f32_16x16x32_bf16(
                    af[i], bfr[j], acc[i][j], 0, 0, 0);
        __syncthreads();
    }

#pragma unroll
    for (int i = 0; i < 2; ++i)
#pragma unroll
        for (int p = 0; p < 4; ++p) {
            const int r = wm + i * 16 + quad * 4 + p;
#pragma unroll
            for (int j = 0; j < 2; ++j) {
                const int c = wn + j * 16 + lrow;
                s[(long)z * 4096 + r * 64 + c] = acc[i][j][p] * 0.03125f;
            }
        }
}

// ---------------------------------------------------------------------------
// Sinkhorn: 256 threads/block; wave w handles a 16-wide slice.
// ---------------------------------------------------------------------------
__global__ __launch_bounds__(256) void sinkhorn_kernel(float* __restrict__ s)
{
    const int z = blockIdx.x;
    const int t = threadIdx.x;
    const int lane = t & 63;
    const int w = t >> 6;
    __shared__ float la[64 * 65];
    __shared__ float pm[4][64], ps[4][64];

    const float4* src = (const float4*)(s + (long)z * 4096);
#pragma unroll
    for (int i = 0; i < 4; ++i) {
        int idx = t + i * 256;
        float4 vv = src[idx];
        int r = idx >> 4, c = (idx & 15) * 4;
        la[r * 65 + c]     = vv.x;
        la[r * 65 + c + 1] = vv.y;
        la[r * 65 + c + 2] = vv.z;
        la[r * 65 + c + 3] = vv.w;
    }
    __syncthreads();

    for (int it = 0; it < 50; ++it) {
        {
            float vr[16];
            float m = -INFINITY;
#pragma unroll
            for (int i = 0; i < 16; ++i) { vr[i] = la[lane * 65 + w * 16 + i]; m = fmaxf(m, vr[i]); }
            float sum = 0.f;
#pragma unroll
            for (int i = 0; i < 16; ++i) sum += __expf(vr[i] - m);
            pm[w][lane] = m; ps[w][lane] = sum;
            __syncthreads();
            float m0 = pm[0][lane], m1 = pm[1][lane], m2 = pm[2][lane], m3 = pm[3][lane];
            float M = fmaxf(fmaxf(m0, m1), fmaxf(m2, m3));
            float S = ps[0][lane] * __expf(m0 - M) + ps[1][lane] * __expf(m1 - M)
                    + ps[2][lane] * __expf(m2 - M) + ps[3][lane] * __expf(m3 - M);
            float lse = M + __logf(S);
#pragma unroll
            for (int i = 0; i < 16; ++i) la[lane * 65 + w * 16 + i] = vr[i] - lse;
            __syncthreads();
        }
        {
            float vr[16];
            float m = -INFINITY;
#pragma unroll
            for (int i = 0; i < 16; ++i) { vr[i] = la[(w * 16 + i) * 65 + lane]; m = fmaxf(m, vr[i]); }
            float sum = 0.f;
#pragma unroll
            for (int i = 0; i < 16; ++i) sum += __expf(vr[i] - m);
            pm[w][lane] = m; ps[w][lane] = sum;
            __syncthreads();
            float m0 = pm[0][lane], m1 = pm[1][lane], m2 = pm[2][lane], m3 = pm[3][lane];
            float M = fmaxf(fmaxf(m0, m1), fmaxf(m2, m3));
            float S = ps[0][lane] * __expf(m0 - M) + ps[1][lane] * __expf(m1 - M)
                    + ps[2][lane] * __expf(m2 - M) + ps[3][lane] * __expf(m3 - M);
            float lse = M + __logf(S);
#pragma unroll
            for (int i = 0; i < 16; ++i) la[(w * 16 + i) * 65 + lane] = vr[i] - lse;
            __syncthreads();
        }
    }
#pragma unroll
    for (int i = 0; i < 4; ++i) {
        int idx = t + i * 256;
        int r = idx >> 4, c = (idx & 15) * 4;
        float4 o;
        o.x = __expf(la[r * 65 + c]);
        o.y = __expf(la[r * 65 + c + 1]);
        o.z = __expf(la[r * 65 + c + 2]);
        o.w = __expf(la[r * 65 + c + 3]);
        ((float4*)(s + (long)z * 4096))[idx] = o;
    }
}

// ---------------------------------------------------------------------------
// attended = attn @ V (V = qkv cols 2048.., stride 3072)
// ---------------------------------------------------------------------------
__global__ __launch_bounds__(256) void attn_v_kernel(
    const float* __restrict__ attn, const __bf16* __restrict__ qkv, float* __restrict__ out)
{
    const int z = blockIdx.y;
    const int n = blockIdx.x * 64 + threadIdx.x;
    __shared__ float Ss[64 * 65];
    const int tid = threadIdx.y * 64 + threadIdx.x;
#pragma unroll
    for (int t = 0; t < 16; ++t) {
        int idx = tid + t * 256;
        int r = idx >> 6, c = idx & 63;
        Ss[r * 65 + c] = attn[(long)z * 4096 + idx];
    }
    __syncthreads();

    const __bf16* v = qkv + 2048;
    float acc[16] = {};
    for (int c = 0; c < 64; ++c) {
        float vv = (float)v[(long)(z * 64 + c) * 3072 + n];
#pragma unroll
        for (int ii = 0; ii < 16; ++ii)
            acc[ii] += Ss[(threadIdx.y * 16 + ii) * 65 + c] * vv;
    }
#pragma unroll
    for (int ii = 0; ii < 16; ++ii)
        out[(long)(z * 64 + threadIdx.y * 16 + ii) * HH_ + n] = acc[ii];
}

// ---------------------------------------------------------------------------
// mix + signal-bound + residual; if doLN: inter-LN (writes h) AND next layer's
// pre-LN (writes nsb_out bf16). Else writes h and bf16 h copy.
// ---------------------------------------------------------------------------
__global__ __launch_bounds__(256) void mix_kernel(
    const __bf16* __restrict__ nsb_in, const float* __restrict__ att,
    const float* __restrict__ ab, const float* __restrict__ sf,
    float* __restrict__ h,
    const float* __restrict__ ig, const float* __restrict__ ib,
    const float* __restrict__ g2, const float* __restrict__ b2p, int doLN,
    __bf16* __restrict__ nsb_out, __bf16* __restrict__ hbf)
{
    __shared__ float s1[256], s2[256];
    const long row = blockIdx.x;
    const int a = (int)(row & 63);
    const int t = threadIdx.x;

    bf16x4 nvb = ((const bf16x4*)(nsb_in + row * HH_))[t];
    float4 av = ((const float4*)(att + row * HH_))[t];
    float4 abv = ((const float4*)(ab + (long)a * HH_))[t];
    float sfa = sf[a];

    float4 sc;
    sc.x = (0.1f * (float)nvb[0] + 0.9f * av.x + abv.x) * sfa;
    sc.y = (0.1f * (float)nvb[1] + 0.9f * av.y + abv.y) * sfa;
    sc.z = (0.1f * (float)nvb[2] + 0.9f * av.z + abv.z) * sfa;
    sc.w = (0.1f * (float)nvb[3] + 0.9f * av.w + abv.w) * sfa;

    s1[t] = sc.x * sc.x + sc.y * sc.y + sc.z * sc.z + sc.w * sc.w;
    __syncthreads();
    for (int off = 128; off > 0; off >>= 1) {
        if (t < off) s1[t] += s1[t + off];
        __syncthreads();
    }
    float norm = sqrtf(s1[0]);
    float inv = norm > 1.0f ? 1.0f / norm : 1.0f;

    float4 hv = ((const float4*)(h + row * HH_))[t];
    float4 hn;
    hn.x = hv.x + sc.x * inv;
    hn.y = hv.y + sc.y * inv;
    hn.z = hv.z + sc.z * inv;
    hn.w = hv.w + sc.w * inv;

    if (!doLN) {
        ((float4*)(h + row * HH_))[t] = hn;
        bf16x4 ob = {(__bf16)hn.x, (__bf16)hn.y, (__bf16)hn.z, (__bf16)hn.w};
        ((bf16x4*)(hbf + row * HH_))[t] = ob;
        return;
    }
    // inter-layer LN
    __syncthreads();
    s1[t] = hn.x + hn.y + hn.z + hn.w;
    s2[t] = hn.x * hn.x + hn.y * hn.y + hn.z * hn.z + hn.w * hn.w;
    __syncthreads();
    for (int off = 128; off > 0; off >>= 1) {
        if (t < off) { s1[t] += s1[t + off]; s2[t] += s2[t + off]; }
        __syncthreads();
    }
    float mu = s1[0] * (1.0f / 1024.0f);
    float var = s2[0] * (1.0f / 1024.0f) - mu * mu;
    float rstd = rsqrtf(var + 1e-5f);
    float4 gv = ((const float4*)ig)[t];
    float4 bv = ((const float4*)ib)[t];
    hn.x = (hn.x - mu) * rstd * gv.x + bv.x;
    hn.y = (hn.y - mu) * rstd * gv.y + bv.y;
    hn.z = (hn.z - mu) * rstd * gv.z + bv.z;
    hn.w = (hn.w - mu) * rstd * gv.w + bv.w;
    ((float4*)(h + row * HH_))[t] = hn;

    // next layer's pre-LN -> nsb_out (bf16)
    __syncthreads();
    s1[t] = hn.x + hn.y + hn.z + hn.w;
    s2[t] = hn.x * hn.x + hn.y * hn.y + hn.z * hn.z + hn.w * hn.w;
    __syncthreads();
    for (int off = 128; off > 0; off >>= 1) {
        if (t < off) { s1[t] += s1[t + off]; s2[t] += s2[t + off]; }
        __syncthreads();
    }
    mu = s1[0] * (1.0f / 1024.0f);
    var = s2[0] * (1.0f / 1024.0f) - mu * mu;
    rstd = rsqrtf(var + 1e-5f);
    float4 g2v = ((const float4*)g2)[t];
    float4 b2v = ((const float4*)b2p)[t];
    bf16x4 ob = {(__bf16)((hn.x - mu) * rstd * g2v.x + b2v.x),
                 (__bf16)((hn.y - mu) * rstd * g2v.y + b2v.y),
                 (__bf16)((hn.z - mu) * rstd * g2v.z + b2v.z),
                 (__bf16)((hn.w - mu) * rstd * g2v.w + b2v.w)};
    ((bf16x4*)(nsb_out + row * HH_))[t] = ob;
}

// ---------------------------------------------------------------------------
extern "C" void kernel_launch(void* const* d_in, const int* in_sizes, int n_in,
                              void* d_out, int out_size, void* d_ws, size_t ws_size,
                              hipStream_t stream)
{
    const float* agent_states = (const float*)d_in[0];
    const float* Win   = (const float*)d_in[1];
    const float* bin_  = (const float*)d_in[2];
    const float* ln_g  = (const float*)d_in[3];
    const float* ln_b  = (const float*)d_in[4];
    const float* Wq    = (const float*)d_in[5];
    const float* bq    = (const float*)d_in[6];
    const float* Wk    = (const float*)d_in[7];
    const float* bk    = (const float*)d_in[8];
    const float* Wv    = (const float*)d_in[9];
    const float* bv    = (const float*)d_in[10];
    const float* ab    = (const float*)d_in[11];
    const float* sf    = (const float*)d_in[12];
    const float* ilg   = (const float*)d_in[13];
    const float* ilb   = (const float*)d_in[14];
    const float* W1    = (const float*)d_in[15];
    const float* b1    = (const float*)d_in[16];
    const float* W2    = (const float*)d_in[17];
    const float* b2    = (const float*)d_in[18];
    float* out = (float*)d_out;

    // ---- workspace layout ----
    float* ws_f = (float*)d_ws;
    float* h     = ws_f;                       // HN
    float* att   = ws_f + HN;                  // HN   (post-loop: W2t + yb overlay)
    float* sc    = ws_f + 2 * HN;              // 1,048,576
    float* qbias = ws_f + 2 * HN + 1048576;    // 16384 (9216 used)

    __bf16* base = (__bf16*)(ws_f + 2 * HN + 1048576 + 16384);
    __bf16* nsb   = base;                      // HN
    __bf16* qkvb  = nsb + HN;                  // ROWS*3072 = 50,331,648
    __bf16* hb    = qkvb + (long)ROWS * 3072;  // HN
    __bf16* Wqkvt = hb + HN;                   // 3 * 3 * 1,048,576
    __bf16* P     = Wqkvt + 3L * 3 * 1048576;  // 33,554,432 elems
    // pre-loop overlays in P:
    __bf16* asb  = P;                          // 8,388,608
    __bf16* Wint = P + 8388608;                // 524,288
    // post-loop overlays:
    __bf16* W1t = P;                           // 33,554,432
    __bf16* W2t = (__bf16*)att;                // 8,388,608
    __bf16* yb  = (__bf16*)att + 8388608;      // 8,388,608

    // ---- prep: casts / packs ----
    cast_kernel<<<8192, 256, 0, stream>>>(agent_states, asb);
    transpose_cast_kernel<<<dim3(32, 16, 1), 256, 0, stream>>>(Win, Wint, 512, 1024, 0, 0);
    // fused QKV weights: Wqkvt[l] = [Wq^T | Wk^T | Wv^T] as [3072][1024]
    transpose_cast_kernel<<<dim3(32, 32, 3), 256, 0, stream>>>(Wq, Wqkvt,
                                                               1024, 1024, 1048576, 3145728);
    transpose_cast_kernel<<<dim3(32, 32, 3), 256, 0, stream>>>(Wk, Wqkvt + 1048576,
                                                               1024, 1024, 1048576, 3145728);
    transpose_cast_kernel<<<dim3(32, 32, 3), 256, 0, stream>>>(Wv, Wqkvt + 2097152,
                                                               1024, 1024, 1048576, 3145728);
    qkv_bias_kernel<<<36, 256, 0, stream>>>(bq, bk, bv, qbias);

    // ---- input projection ----
    mfma_gemm<0, 0><<<dim3(8, 128, 1), 256, 0, stream>>>(
        asb, Wint, bin_, h, nullptr, ROWS, HH_, DIN, DIN, DIN, HH_, 0, 0, 0, 0);
    ln_kernel<<<ROWS, 256, 0, stream>>>(h, ln_g, ln_b, nsb);

    for (int i = 0; i < LL; ++i) {
        // fused QKV: [16384,1024] @ [1024,3072]
        mfma_gemm<0, 1><<<dim3(24, 128, 1), 256, 0, stream>>>(
            nsb, Wqkvt + (long)i * 3145728, qbias + i * 3072, nullptr, qkvb,
            ROWS, 3072, HH_, HH_, HH_, 3072, 0, 0, 0, 0);
        scores_mfma_kernel<<<BB, 256, 0, stream>>>(qkvb, sc);
        sinkhorn_kernel<<<BB, 256, 0, stream>>>(sc);
        attn_v_kernel<<<dim3(16, BB), dim3(64, 4), 0, stream>>>(sc, qkvb, att);
        const int last = (i == LL - 1);
        mix_kernel<<<ROWS, 256, 0, stream>>>(
            nsb, att, ab + (long)i * AA * HH_, sf + i * AA, h,
            ilg + (last ? 0 : i) * HH_, ilb + (last ? 0 : i) * HH_,
            ln_g + (last ? 0 : (i + 1)) * HH_, ln_b + (last ? 0 : (i + 1)) * HH_,
            last ? 0 : 1, nsb, hb);
    }

    // ---- heads ----
    transpose_cast_kernel<<<dim3(16, 32, 64), 256, 0, stream>>>(W1, W1t, 1024, 512,
                                                                524288, 524288);
    transpose_cast_kernel<<<dim3(8, 16, 64), 256, 0, stream>>>(W2, W2t, 512, 256,
                                                               131072, 131072);
    mfma_gemm<1, 1><<<dim3(4, 2, 64), 256, 0, stream>>>(
        hb, W1t, b1, nullptr, yb, BB, HHALF, HH_,
        AA * HH_, HH_, AA * HHALF, HH_, (long)HHALF * HH_, HHALF, HHALF);
    mfma_gemm<0, 0><<<dim3(2, 2, 64), 256, 0, stream>>>(
        yb, W2t, b2, out, nullptr, BB, OUTD, HHALF,
        AA * HHALF, HHALF, AA * OUTD, HHALF, (long)OUTD * HHALF, OUTD, OUTD);
}

// Round 4
// 1194.235 us; speedup vs baseline: 7.2473x; 1.1732x over previous
//
#include <hip/hip_runtime.h>
#include <hip/hip_bf16.h>
#include <math.h>

// Problem constants
#define BB 256
#define AA 64
#define DIN 512
#define HH_ 1024
#define HHALF 512
#define OUTD 256
#define LL 3
#define ROWS (BB * AA)          // 16384
#define HN ((long)ROWS * HH_)   // 16,777,216 elements per activation buffer

typedef float f32x4 __attribute__((ext_vector_type(4)));
typedef __bf16 bf16x8 __attribute__((ext_vector_type(8)));
typedef __bf16 bf16x4 __attribute__((ext_vector_type(4)));

__device__ __forceinline__ void gld_lds16(const void* g, void* l) {
    __builtin_amdgcn_global_load_lds(
        (const __attribute__((address_space(1))) unsigned int*)g,
        (__attribute__((address_space(3))) unsigned int*)l, 16, 0, 0);
}

// ---------------------------------------------------------------------------
// bf16 MFMA GEMM (m97 structure): C = act(A @ Bt^T + bias)
// A: [M][K] bf16 (lda). Bt: [N][K] bf16 (ldb). 128x128 tile, BK=32,
// 256 thr = 4 waves, each wave 64x64 via 4x4 16x16x32 MFMA. Batched over z.
// SWZ=1: XCD-aware remap for the 24x128 QKV grid (n-half x m-band per XCD).
// ---------------------------------------------------------------------------
#define TK 32
template <int ACT, int OUT_BF16, int SWZ>  // ACT: 1 = exact GELU
__global__ __launch_bounds__(256) void mfma_gemm(
    const __bf16* __restrict__ Abase, const __bf16* __restrict__ Btbase,
    const float* __restrict__ biasBase, float* __restrict__ Cf,
    __bf16* __restrict__ Cb,
    int M, int N, int K, int lda, int ldb, int ldc,
    long sA, long sB, long sBias, long sC)
{
    const int z = blockIdx.z;
    const __bf16* A  = Abase  + (long)z * sA;
    const __bf16* Bt = Btbase + (long)z * sB;
    const float* bias = biasBase + (long)z * sBias;

    int bx = blockIdx.x, by = blockIdx.y;
    if (SWZ) {  // grid must be 24 x 128
        int lid = by * 24 + bx;
        int xcd = lid & 7, s = lid >> 3;       // s: 0..383
        by = (xcd >> 1) * 32 + s / 12;
        bx = (xcd & 1) * 12 + s % 12;
    }
    const int m0 = by * 128;
    const int n0 = bx * 128;

    __shared__ __bf16 sAt[128 * TK];   // [m][k]
    __shared__ __bf16 sBt[128 * TK];   // [n][k]

    const int t    = threadIdx.x;
    const int wv   = t >> 6;
    const int lane = t & 63;
    const int quad = lane >> 4;
    const int lrow = lane & 15;
    const int wm = (wv >> 1) * 64;
    const int wn = (wv & 1) * 64;

    f32x4 acc[4][4] = {};

    const int sr = t >> 2;
    const int sk = (t & 3) * 8;
    __bf16* la0 = sAt + wv * 512;
    __bf16* la1 = sAt + 64 * TK + wv * 512;
    __bf16* lb0 = sBt + wv * 512;
    __bf16* lb1 = sBt + 64 * TK + wv * 512;

    for (int k0 = 0; k0 < K; k0 += TK) {
        gld_lds16(A  + (long)(m0 + sr)      * lda + k0 + sk, la0);
        gld_lds16(A  + (long)(m0 + 64 + sr) * lda + k0 + sk, la1);
        gld_lds16(Bt + (long)(n0 + sr)      * ldb + k0 + sk, lb0);
        gld_lds16(Bt + (long)(n0 + 64 + sr) * ldb + k0 + sk, lb1);
        __syncthreads();

        bf16x8 af[4], bfr[4];
#pragma unroll
        for (int i = 0; i < 4; ++i)
            af[i] = *(const bf16x8*)(sAt + (wm + i * 16 + lrow) * TK + quad * 8);
#pragma unroll
        for (int j = 0; j < 4; ++j)
            bfr[j] = *(const bf16x8*)(sBt + (wn + j * 16 + lrow) * TK + quad * 8);
#pragma unroll
        for (int i = 0; i < 4; ++i)
#pragma unroll
            for (int j = 0; j < 4; ++j)
                acc[i][j] = __builtin_amdgcn_mfma_f32_16x16x32_bf16(
                    af[i], bfr[j], acc[i][j], 0, 0, 0);
        __syncthreads();
    }

#pragma unroll
    for (int i = 0; i < 4; ++i) {
#pragma unroll
        for (int p = 0; p < 4; ++p) {
            const int m = m0 + wm + i * 16 + quad * 4 + p;
#pragma unroll
            for (int j = 0; j < 4; ++j) {
                const int n = n0 + wn + j * 16 + lrow;
                float val = acc[i][j][p] + bias[n];
                if (ACT == 1) val = 0.5f * val * (1.0f + erff(val * 0.70710678118654752f));
                if (OUT_BF16) Cb[(long)z * sC + (long)m * ldc + n] = (__bf16)val;
                else          Cf[(long)z * sC + (long)m * ldc + n] = val;
            }
        }
    }
}

// ---------------------------------------------------------------------------
// fp32 -> bf16 flat cast
// ---------------------------------------------------------------------------
__global__ __launch_bounds__(256) void cast_kernel(
    const float* __restrict__ in, __bf16* __restrict__ out)
{
    long i = ((long)blockIdx.x * 256 + threadIdx.x) * 4;
    float4 v = *(const float4*)(in + i);
    bf16x4 o = {(__bf16)v.x, (__bf16)v.y, (__bf16)v.z, (__bf16)v.w};
    *(bf16x4*)(out + i) = o;
}

// ---------------------------------------------------------------------------
// Transpose + cast: fp32 [R][C] -> bf16 [C][R], batched over z.
// ---------------------------------------------------------------------------
__global__ __launch_bounds__(256) void transpose_cast_kernel(
    const float* __restrict__ in, __bf16* __restrict__ out,
    int R, int C, long sIn, long sOut)
{
    const float* src = in + (long)blockIdx.z * sIn;
    __bf16* dst = out + (long)blockIdx.z * sOut;
    __shared__ float tile[32][33];
    const int r0 = blockIdx.y * 32, c0 = blockIdx.x * 32;
    const int tx = threadIdx.x & 31, ty = threadIdx.x >> 5;
#pragma unroll
    for (int i = 0; i < 32; i += 8)
        tile[ty + i][tx] = src[(long)(r0 + ty + i) * C + c0 + tx];
    __syncthreads();
#pragma unroll
    for (int i = 0; i < 32; i += 8)
        dst[(long)(c0 + ty + i) * R + r0 + tx] = (__bf16)tile[tx][ty + i];
}

// ---------------------------------------------------------------------------
// Concatenate bq|bk|bv per layer into [L][3072]
// ---------------------------------------------------------------------------
__global__ __launch_bounds__(256) void qkv_bias_kernel(
    const float* __restrict__ bq, const float* __restrict__ bk,
    const float* __restrict__ bv, float* __restrict__ ob)
{
    int i = blockIdx.x * 256 + threadIdx.x;
    if (i >= LL * 3072) return;
    int l = i / 3072, j = i - l * 3072;
    float v = (j < 1024) ? bq[l * 1024 + j]
            : (j < 2048) ? bk[l * 1024 + j - 1024]
                         : bv[l * 1024 + j - 2048];
    ob[i] = v;
}

// ---------------------------------------------------------------------------
// Row LayerNorm over H=1024, bf16 in -> bf16 out
// ---------------------------------------------------------------------------
__global__ __launch_bounds__(256) void ln_kernel(
    const __bf16* __restrict__ x, const float* __restrict__ g,
    const float* __restrict__ b, __bf16* __restrict__ outb)
{
    __shared__ float s1[256], s2[256];
    const long row = blockIdx.x;
    const int t = threadIdx.x;
    bf16x4 vb = ((const bf16x4*)(x + row * HH_))[t];
    float4 v = {(float)vb[0], (float)vb[1], (float)vb[2], (float)vb[3]};
    s1[t] = v.x + v.y + v.z + v.w;
    s2[t] = v.x * v.x + v.y * v.y + v.z * v.z + v.w * v.w;
    __syncthreads();
    for (int off = 128; off > 0; off >>= 1) {
        if (t < off) { s1[t] += s1[t + off]; s2[t] += s2[t + off]; }
        __syncthreads();
    }
    float mu = s1[0] * (1.0f / 1024.0f);
    float var = s2[0] * (1.0f / 1024.0f) - mu * mu;
    float rstd = rsqrtf(var + 1e-5f);
    float4 gv = ((const float4*)g)[t];
    float4 bv = ((const float4*)b)[t];
    bf16x4 ob = {(__bf16)((v.x - mu) * rstd * gv.x + bv.x),
                 (__bf16)((v.y - mu) * rstd * gv.y + bv.y),
                 (__bf16)((v.z - mu) * rstd * gv.z + bv.z),
                 (__bf16)((v.w - mu) * rstd * gv.w + bv.w)};
    ((bf16x4*)(outb + row * HH_))[t] = ob;
}

// ---------------------------------------------------------------------------
// Fused attention per batch z: scores (MFMA) -> sinkhorn (LDS) -> P@V (MFMA).
// Q/K/V are qkv rows (stride 3072, offsets 0/1024/2048). att out bf16.
// ---------------------------------------------------------------------------
__global__ __launch_bounds__(256) void attn_kernel(
    const __bf16* __restrict__ qkv, __bf16* __restrict__ att)
{
    const int z = blockIdx.x;
    __shared__ __bf16 sQ[64 * 32];
    __shared__ __bf16 sK[64 * 32];
    __shared__ float la[64 * 65];
    __shared__ float pm[4][64], ps[4][64];
    __shared__ __bf16 sP[64 * 68];    // exp(P) bf16, padded (136B rows)
    __shared__ __bf16 sVT[64 * 68];   // V^T tile [n][c], padded

    const int t = threadIdx.x;
    const int wv = t >> 6, lane = t & 63;
    const int quad = lane >> 4, lrow = lane & 15;
    const int wm = (wv >> 1) * 32, wn = (wv & 1) * 32;

    // ---- phase 1: scores = Q K^T / 32 -> la ----
    {
        const int srow = t >> 2;
        const int skoff = (t & 3) * 8;
        __bf16* lq = sQ + wv * 512;
        __bf16* lk = sK + wv * 512;
        const __bf16* Q = qkv + (long)z * 64 * 3072;
        const __bf16* K = Q + 1024;

        f32x4 acc[2][2] = {};
        for (int k0 = 0; k0 < 1024; k0 += 32) {
            gld_lds16(Q + (long)srow * 3072 + k0 + skoff, lq);
            gld_lds16(K + (long)srow * 3072 + k0 + skoff, lk);
            __syncthreads();
            bf16x8 af[2], bfr[2];
#pragma unroll
            for (int i = 0; i < 2; ++i)
                af[i] = *(const bf16x8*)(sQ + (wm + i * 16 + lrow) * 32 + quad * 8);
#pragma unroll
            for (int j = 0; j < 2; ++j)
                bfr[j] = *(const bf16x8*)(sK + (wn + j * 16 + lrow) * 32 + quad * 8);
#pragma unroll
            for (int i = 0; i < 2; ++i)
#pragma unroll
                for (int j = 0; j < 2; ++j)
                    acc[i][j] = __builtin_amdgcn_mfma_f32_16x16x32_bf16(
                        af[i], bfr[j], acc[i][j], 0, 0, 0);
            __syncthreads();
        }
#pragma unroll
        for (int i = 0; i < 2; ++i)
#pragma unroll
            for (int p = 0; p < 4; ++p) {
                const int r = wm + i * 16 + quad * 4 + p;
#pragma unroll
                for (int j = 0; j < 2; ++j)
                    la[r * 65 + wn + j * 16 + lrow] = acc[i][j][p] * 0.03125f;
            }
        __syncthreads();
    }

    // ---- phase 2: sinkhorn, 50 iters ----
    for (int it = 0; it < 50; ++it) {
        {   // row phase: row = lane, cols wv*16..+15
            float vr[16];
            float m = -INFINITY;
#pragma unroll
            for (int i = 0; i < 16; ++i) { vr[i] = la[lane * 65 + wv * 16 + i]; m = fmaxf(m, vr[i]); }
            float sum = 0.f;
#pragma unroll
            for (int i = 0; i < 16; ++i) sum += __expf(vr[i] - m);
            pm[wv][lane] = m; ps[wv][lane] = sum;
            __syncthreads();
            float m0 = pm[0][lane], m1 = pm[1][lane], m2 = pm[2][lane], m3 = pm[3][lane];
            float M = fmaxf(fmaxf(m0, m1), fmaxf(m2, m3));
            float S = ps[0][lane] * __expf(m0 - M) + ps[1][lane] * __expf(m1 - M)
                    + ps[2][lane] * __expf(m2 - M) + ps[3][lane] * __expf(m3 - M);
            float lse = M + __logf(S);
#pragma unroll
            for (int i = 0; i < 16; ++i) la[lane * 65 + wv * 16 + i] = vr[i] - lse;
            __syncthreads();
        }
        {   // col phase: col = lane, rows wv*16..+15
            float vr[16];
            float m = -INFINITY;
#pragma unroll
            for (int i = 0; i < 16; ++i) { vr[i] = la[(wv * 16 + i) * 65 + lane]; m = fmaxf(m, vr[i]); }
            float sum = 0.f;
#pragma unroll
            for (int i = 0; i < 16; ++i) sum += __expf(vr[i] - m);
            pm[wv][lane] = m; ps[wv][lane] = sum;
            __syncthreads();
            float m0 = pm[0][lane], m1 = pm[1][lane], m2 = pm[2][lane], m3 = pm[3][lane];
            float M = fmaxf(fmaxf(m0, m1), fmaxf(m2, m3));
            float S = ps[0][lane] * __expf(m0 - M) + ps[1][lane] * __expf(m1 - M)
                    + ps[2][lane] * __expf(m2 - M) + ps[3][lane] * __expf(m3 - M);
            float lse = M + __logf(S);
#pragma unroll
            for (int i = 0; i < 16; ++i) la[(wv * 16 + i) * 65 + lane] = vr[i] - lse;
            __syncthreads();
        }
    }

    // ---- phase 3: P = exp(la) -> bf16 sP ----
#pragma unroll
    for (int i = 0; i < 16; ++i) {
        int idx = t + i * 256;
        int r = idx >> 6, c = idx & 63;
        sP[r * 68 + c] = (__bf16)__expf(la[r * 65 + c]);
    }
    __syncthreads();

    // ---- phase 4: att = P @ V via MFMA, 16 column tiles of 64 ----
    const __bf16* V = qkv + (long)z * 64 * 3072 + 2048;
    const int vc = t >> 2;            // V row (agent c), 0..63
    const int vn = (t & 3) * 16;      // n offset within tile
    for (int tile = 0; tile < 16; ++tile) {
        bf16x8 v0 = *(const bf16x8*)(V + (long)vc * 3072 + tile * 64 + vn);
        bf16x8 v1 = *(const bf16x8*)(V + (long)vc * 3072 + tile * 64 + vn + 8);
#pragma unroll
        for (int j = 0; j < 8; ++j) sVT[(vn + j) * 68 + vc] = v0[j];
#pragma unroll
        for (int j = 0; j < 8; ++j) sVT[(vn + 8 + j) * 68 + vc] = v1[j];
        __syncthreads();

        f32x4 pacc[2][2] = {};
#pragma unroll
        for (int kb = 0; kb < 2; ++kb) {
            bf16x8 af[2], bfr[2];
#pragma unroll
            for (int i = 0; i < 2; ++i) {
                const __bf16* p = sP + (wm + i * 16 + lrow) * 68 + kb * 32 + quad * 8;
                bf16x4 lo = *(const bf16x4*)p;
                bf16x4 hi = *(const bf16x4*)(p + 4);
                af[i] = bf16x8{lo[0], lo[1], lo[2], lo[3], hi[0], hi[1], hi[2], hi[3]};
            }
#pragma unroll
            for (int j = 0; j < 2; ++j) {
                const __bf16* p = sVT + (wn + j * 16 + lrow) * 68 + kb * 32 + quad * 8;
                bf16x4 lo = *(const bf16x4*)p;
                bf16x4 hi = *(const bf16x4*)(p + 4);
                bfr[j] = bf16x8{lo[0], lo[1], lo[2], lo[3], hi[0], hi[1], hi[2], hi[3]};
            }
#pragma unroll
            for (int i = 0; i < 2; ++i)
#pragma unroll
                for (int j = 0; j < 2; ++j)
                    pacc[i][j] = __builtin_amdgcn_mfma_f32_16x16x32_bf16(
                        af[i], bfr[j], pacc[i][j], 0, 0, 0);
        }
#pragma unroll
        for (int i = 0; i < 2; ++i)
#pragma unroll
            for (int p = 0; p < 4; ++p) {
                const int r = wm + i * 16 + quad * 4 + p;
#pragma unroll
                for (int j = 0; j < 2; ++j) {
                    const int n = tile * 64 + wn + j * 16 + lrow;
                    att[((long)z * 64 + r) * HH_ + n] = (__bf16)pacc[i][j][p];
                }
            }
        __syncthreads();   // protect sVT overwrite next tile
    }
}

// ---------------------------------------------------------------------------
// mix + signal-bound + residual (h bf16); if doLN: inter-LN (-> h) and next
// layer's pre-LN (-> nsb_out).
// ---------------------------------------------------------------------------
__global__ __launch_bounds__(256) void mix_kernel(
    const __bf16* __restrict__ nsb_in, const __bf16* __restrict__ att,
    const float* __restrict__ ab, const float* __restrict__ sf,
    __bf16* __restrict__ h,
    const float* __restrict__ ig, const float* __restrict__ ib,
    const float* __restrict__ g2, const float* __restrict__ b2p, int doLN,
    __bf16* __restrict__ nsb_out)
{
    __shared__ float s1[256], s2[256];
    const long row = blockIdx.x;
    const int a = (int)(row & 63);
    const int t = threadIdx.x;

    bf16x4 nvb = ((const bf16x4*)(nsb_in + row * HH_))[t];
    bf16x4 avb = ((const bf16x4*)(att + row * HH_))[t];
    float4 abv = ((const float4*)(ab + (long)a * HH_))[t];
    float sfa = sf[a];

    float4 sc;
    sc.x = (0.1f * (float)nvb[0] + 0.9f * (float)avb[0] + abv.x) * sfa;
    sc.y = (0.1f * (float)nvb[1] + 0.9f * (float)avb[1] + abv.y) * sfa;
    sc.z = (0.1f * (float)nvb[2] + 0.9f * (float)avb[2] + abv.z) * sfa;
    sc.w = (0.1f * (float)nvb[3] + 0.9f * (float)avb[3] + abv.w) * sfa;

    s1[t] = sc.x * sc.x + sc.y * sc.y + sc.z * sc.z + sc.w * sc.w;
    __syncthreads();
    for (int off = 128; off > 0; off >>= 1) {
        if (t < off) s1[t] += s1[t + off];
        __syncthreads();
    }
    float norm = sqrtf(s1[0]);
    float inv = norm > 1.0f ? 1.0f / norm : 1.0f;

    bf16x4 hvb = ((const bf16x4*)(h + row * HH_))[t];
    float4 hn;
    hn.x = (float)hvb[0] + sc.x * inv;
    hn.y = (float)hvb[1] + sc.y * inv;
    hn.z = (float)hvb[2] + sc.z * inv;
    hn.w = (float)hvb[3] + sc.w * inv;

    if (!doLN) {
        bf16x4 ob = {(__bf16)hn.x, (__bf16)hn.y, (__bf16)hn.z, (__bf16)hn.w};
        ((bf16x4*)(h + row * HH_))[t] = ob;
        return;
    }
    // inter-layer LN -> h
    __syncthreads();
    s1[t] = hn.x + hn.y + hn.z + hn.w;
    s2[t] = hn.x * hn.x + hn.y * hn.y + hn.z * hn.z + hn.w * hn.w;
    __syncthreads();
    for (int off = 128; off > 0; off >>= 1) {
        if (t < off) { s1[t] += s1[t + off]; s2[t] += s2[t + off]; }
        __syncthreads();
    }
    float mu = s1[0] * (1.0f / 1024.0f);
    float var = s2[0] * (1.0f / 1024.0f) - mu * mu;
    float rstd = rsqrtf(var + 1e-5f);
    float4 gv = ((const float4*)ig)[t];
    float4 bv = ((const float4*)ib)[t];
    hn.x = (hn.x - mu) * rstd * gv.x + bv.x;
    hn.y = (hn.y - mu) * rstd * gv.y + bv.y;
    hn.z = (hn.z - mu) * rstd * gv.z + bv.z;
    hn.w = (hn.w - mu) * rstd * gv.w + bv.w;
    bf16x4 ob = {(__bf16)hn.x, (__bf16)hn.y, (__bf16)hn.z, (__bf16)hn.w};
    ((bf16x4*)(h + row * HH_))[t] = ob;

    // next layer's pre-LN -> nsb_out
    __syncthreads();
    s1[t] = hn.x + hn.y + hn.z + hn.w;
    s2[t] = hn.x * hn.x + hn.y * hn.y + hn.z * hn.z + hn.w * hn.w;
    __syncthreads();
    for (int off = 128; off > 0; off >>= 1) {
        if (t < off) { s1[t] += s1[t + off]; s2[t] += s2[t + off]; }
        __syncthreads();
    }
    mu = s1[0] * (1.0f / 1024.0f);
    var = s2[0] * (1.0f / 1024.0f) - mu * mu;
    rstd = rsqrtf(var + 1e-5f);
    float4 g2v = ((const float4*)g2)[t];
    float4 b2v = ((const float4*)b2p)[t];
    bf16x4 o2 = {(__bf16)((hn.x - mu) * rstd * g2v.x + b2v.x),
                 (__bf16)((hn.y - mu) * rstd * g2v.y + b2v.y),
                 (__bf16)((hn.z - mu) * rstd * g2v.z + b2v.z),
                 (__bf16)((hn.w - mu) * rstd * g2v.w + b2v.w)};
    ((bf16x4*)(nsb_out + row * HH_))[t] = o2;
}

// ---------------------------------------------------------------------------
extern "C" void kernel_launch(void* const* d_in, const int* in_sizes, int n_in,
                              void* d_out, int out_size, void* d_ws, size_t ws_size,
                              hipStream_t stream)
{
    const float* agent_states = (const float*)d_in[0];
    const float* Win   = (const float*)d_in[1];
    const float* bin_  = (const float*)d_in[2];
    const float* ln_g  = (const float*)d_in[3];
    const float* ln_b  = (const float*)d_in[4];
    const float* Wq    = (const float*)d_in[5];
    const float* bq    = (const float*)d_in[6];
    const float* Wk    = (const float*)d_in[7];
    const float* bk    = (const float*)d_in[8];
    const float* Wv    = (const float*)d_in[9];
    const float* bv    = (const float*)d_in[10];
    const float* ab    = (const float*)d_in[11];
    const float* sf    = (const float*)d_in[12];
    const float* ilg   = (const float*)d_in[13];
    const float* ilb   = (const float*)d_in[14];
    const float* W1    = (const float*)d_in[15];
    const float* b1    = (const float*)d_in[16];
    const float* W2    = (const float*)d_in[17];
    const float* b2    = (const float*)d_in[18];
    float* out = (float*)d_out;

    // ---- workspace layout ----
    float* qbias = (float*)d_ws;                 // 16384 floats (9216 used)
    __bf16* base = (__bf16*)(qbias + 16384);
    __bf16* nsb   = base;                        // HN
    __bf16* h     = nsb + HN;                    // HN
    __bf16* att   = h + HN;                      // HN
    __bf16* qkvb  = att + HN;                    // 3*HN = 50,331,648
    __bf16* Wqkvt = qkvb + 3 * HN;               // 9,437,184
    // pre-loop overlays (att unused until layer 0 attention):
    __bf16* asb  = att;                          // 8,388,608
    __bf16* Wint = att + 8388608;                // 524,288
    // post-loop overlays (qkvb dead after last attention):
    __bf16* W1t = qkvb;                          // 33,554,432
    __bf16* W2t = qkvb + 33554432;               // 8,388,608
    __bf16* yb  = qkvb + 41943040;               // 8,388,608

    // ---- prep: casts / packs ----
    cast_kernel<<<8192, 256, 0, stream>>>(agent_states, asb);
    transpose_cast_kernel<<<dim3(32, 16, 1), 256, 0, stream>>>(Win, Wint, 512, 1024, 0, 0);
    transpose_cast_kernel<<<dim3(32, 32, 3), 256, 0, stream>>>(Wq, Wqkvt,
                                                               1024, 1024, 1048576, 3145728);
    transpose_cast_kernel<<<dim3(32, 32, 3), 256, 0, stream>>>(Wk, Wqkvt + 1048576,
                                                               1024, 1024, 1048576, 3145728);
    transpose_cast_kernel<<<dim3(32, 32, 3), 256, 0, stream>>>(Wv, Wqkvt + 2097152,
                                                               1024, 1024, 1048576, 3145728);
    qkv_bias_kernel<<<36, 256, 0, stream>>>(bq, bk, bv, qbias);

    // ---- input projection: h(bf16) = asb @ Win^T + bin ----
    mfma_gemm<0, 1, 0><<<dim3(8, 128, 1), 256, 0, stream>>>(
        asb, Wint, bin_, nullptr, h, ROWS, HH_, DIN, DIN, DIN, HH_, 0, 0, 0, 0);
    ln_kernel<<<ROWS, 256, 0, stream>>>(h, ln_g, ln_b, nsb);

    for (int i = 0; i < LL; ++i) {
        mfma_gemm<0, 1, 1><<<dim3(24, 128, 1), 256, 0, stream>>>(
            nsb, Wqkvt + (long)i * 3145728, qbias + i * 3072, nullptr, qkvb,
            ROWS, 3072, HH_, HH_, HH_, 3072, 0, 0, 0, 0);
        attn_kernel<<<BB, 256, 0, stream>>>(qkvb, att);
        const int last = (i == LL - 1);
        mix_kernel<<<ROWS, 256, 0, stream>>>(
            nsb, att, ab + (long)i * AA * HH_, sf + i * AA, h,
            ilg + (last ? 0 : i) * HH_, ilb + (last ? 0 : i) * HH_,
            ln_g + (last ? 0 : (i + 1)) * HH_, ln_b + (last ? 0 : (i + 1)) * HH_,
            last ? 0 : 1, nsb);
    }

    // ---- heads ----
    transpose_cast_kernel<<<dim3(16, 32, 64), 256, 0, stream>>>(W1, W1t, 1024, 512,
                                                                524288, 524288);
    transpose_cast_kernel<<<dim3(8, 16, 64), 256, 0, stream>>>(W2, W2t, 512, 256,
                                                               131072, 131072);
    mfma_gemm<1, 1, 0><<<dim3(4, 2, 64), 256, 0, stream>>>(
        h, W1t, b1, nullptr, yb, BB, HHALF, HH_,
        AA * HH_, HH_, AA * HHALF, HH_, (long)HHALF * HH_, HHALF, HHALF);
    mfma_gemm<0, 0, 0><<<dim3(2, 2, 64), 256, 0, stream>>>(
        yb, W2t, b2, out, nullptr, BB, OUTD, HHALF,
        AA * HHALF, HHALF, AA * OUTD, HHALF, (long)OUTD * HHALF, OUTD, OUTD);
}

// Round 5
// 1135.851 us; speedup vs baseline: 7.6198x; 1.0514x over previous
//
#include <hip/hip_runtime.h>
#include <hip/hip_bf16.h>
#include <math.h>

// Problem constants
#define BB 256
#define AA 64
#define DIN 512
#define HH_ 1024
#define HHALF 512
#define OUTD 256
#define LL 3
#define ROWS (BB * AA)          // 16384
#define HN ((long)ROWS * HH_)   // 16,777,216 elements per activation buffer

typedef float f32x4 __attribute__((ext_vector_type(4)));
typedef __bf16 bf16x8 __attribute__((ext_vector_type(8)));
typedef __bf16 bf16x4 __attribute__((ext_vector_type(4)));

__device__ __forceinline__ void gld_lds16(const void* g, void* l) {
    __builtin_amdgcn_global_load_lds(
        (const __attribute__((address_space(1))) unsigned int*)g,
        (__attribute__((address_space(3))) unsigned int*)l, 16, 0, 0);
}

// ---------------------------------------------------------------------------
// bf16 MFMA GEMM (m97 structure): C = act(A @ Bt^T + bias)
// ---------------------------------------------------------------------------
#define TK 32
template <int ACT, int OUT_BF16, int SWZ>  // ACT: 1 = exact GELU
__global__ __launch_bounds__(256) void mfma_gemm(
    const __bf16* __restrict__ Abase, const __bf16* __restrict__ Btbase,
    const float* __restrict__ biasBase, float* __restrict__ Cf,
    __bf16* __restrict__ Cb,
    int M, int N, int K, int lda, int ldb, int ldc,
    long sA, long sB, long sBias, long sC)
{
    const int z = blockIdx.z;
    const __bf16* A  = Abase  + (long)z * sA;
    const __bf16* Bt = Btbase + (long)z * sB;
    const float* bias = biasBase + (long)z * sBias;

    int bx = blockIdx.x, by = blockIdx.y;
    if (SWZ) {  // grid must be 24 x 128
        int lid = by * 24 + bx;
        int xcd = lid & 7, s = lid >> 3;       // s: 0..383
        by = (xcd >> 1) * 32 + s / 12;
        bx = (xcd & 1) * 12 + s % 12;
    }
    const int m0 = by * 128;
    const int n0 = bx * 128;

    __shared__ __bf16 sAt[128 * TK];   // [m][k]
    __shared__ __bf16 sBt[128 * TK];   // [n][k]

    const int t    = threadIdx.x;
    const int wv   = t >> 6;
    const int lane = t & 63;
    const int quad = lane >> 4;
    const int lrow = lane & 15;
    const int wm = (wv >> 1) * 64;
    const int wn = (wv & 1) * 64;

    f32x4 acc[4][4] = {};

    const int sr = t >> 2;
    const int sk = (t & 3) * 8;
    __bf16* la0 = sAt + wv * 512;
    __bf16* la1 = sAt + 64 * TK + wv * 512;
    __bf16* lb0 = sBt + wv * 512;
    __bf16* lb1 = sBt + 64 * TK + wv * 512;

    for (int k0 = 0; k0 < K; k0 += TK) {
        gld_lds16(A  + (long)(m0 + sr)      * lda + k0 + sk, la0);
        gld_lds16(A  + (long)(m0 + 64 + sr) * lda + k0 + sk, la1);
        gld_lds16(Bt + (long)(n0 + sr)      * ldb + k0 + sk, lb0);
        gld_lds16(Bt + (long)(n0 + 64 + sr) * ldb + k0 + sk, lb1);
        __syncthreads();

        bf16x8 af[4], bfr[4];
#pragma unroll
        for (int i = 0; i < 4; ++i)
            af[i] = *(const bf16x8*)(sAt + (wm + i * 16 + lrow) * TK + quad * 8);
#pragma unroll
        for (int j = 0; j < 4; ++j)
            bfr[j] = *(const bf16x8*)(sBt + (wn + j * 16 + lrow) * TK + quad * 8);
#pragma unroll
        for (int i = 0; i < 4; ++i)
#pragma unroll
            for (int j = 0; j < 4; ++j)
                acc[i][j] = __builtin_amdgcn_mfma_f32_16x16x32_bf16(
                    af[i], bfr[j], acc[i][j], 0, 0, 0);
        __syncthreads();
    }

#pragma unroll
    for (int i = 0; i < 4; ++i) {
#pragma unroll
        for (int p = 0; p < 4; ++p) {
            const int m = m0 + wm + i * 16 + quad * 4 + p;
#pragma unroll
            for (int j = 0; j < 4; ++j) {
                const int n = n0 + wn + j * 16 + lrow;
                float val = acc[i][j][p] + bias[n];
                if (ACT == 1) val = 0.5f * val * (1.0f + erff(val * 0.70710678118654752f));
                if (OUT_BF16) Cb[(long)z * sC + (long)m * ldc + n] = (__bf16)val;
                else          Cf[(long)z * sC + (long)m * ldc + n] = val;
            }
        }
    }
}

// ---------------------------------------------------------------------------
// fp32 -> bf16 flat cast
// ---------------------------------------------------------------------------
__global__ __launch_bounds__(256) void cast_kernel(
    const float* __restrict__ in, __bf16* __restrict__ out)
{
    long i = ((long)blockIdx.x * 256 + threadIdx.x) * 4;
    float4 v = *(const float4*)(in + i);
    bf16x4 o = {(__bf16)v.x, (__bf16)v.y, (__bf16)v.z, (__bf16)v.w};
    *(bf16x4*)(out + i) = o;
}

// ---------------------------------------------------------------------------
// Generic transpose + cast: fp32 [R][C] -> bf16 [C][R], batched over z.
// ---------------------------------------------------------------------------
__global__ __launch_bounds__(256) void transpose_cast_kernel(
    const float* __restrict__ in, __bf16* __restrict__ out,
    int R, int C, long sIn, long sOut)
{
    const float* src = in + (long)blockIdx.z * sIn;
    __bf16* dst = out + (long)blockIdx.z * sOut;
    __shared__ float tile[32][33];
    const int r0 = blockIdx.y * 32, c0 = blockIdx.x * 32;
    const int tx = threadIdx.x & 31, ty = threadIdx.x >> 5;
#pragma unroll
    for (int i = 0; i < 32; i += 8)
        tile[ty + i][tx] = src[(long)(r0 + ty + i) * C + c0 + tx];
    __syncthreads();
#pragma unroll
    for (int i = 0; i < 32; i += 8)
        dst[(long)(c0 + ty + i) * R + r0 + tx] = (__bf16)tile[tx][ty + i];
}

// ---------------------------------------------------------------------------
// Merged Wq/Wk/Wv transpose: z in [0,9) -> layer z/3, tensor z%3.
// Each 1024x1024 fp32 -> bf16 [1024][1024] transposed, packed per layer as
// [Wq^T | Wk^T | Wv^T] (3072 x 1024).
// ---------------------------------------------------------------------------
__global__ __launch_bounds__(256) void transpose_qkv_kernel(
    const float* __restrict__ Wq, const float* __restrict__ Wk,
    const float* __restrict__ Wv, __bf16* __restrict__ out)
{
    const int zz = blockIdx.z;
    const int layer = zz / 3, which = zz - layer * 3;
    const float* src = (which == 0 ? Wq : which == 1 ? Wk : Wv) + (long)layer * 1048576;
    __bf16* dst = out + (long)layer * 3145728 + (long)which * 1048576;
    __shared__ float tile[32][33];
    const int r0 = blockIdx.y * 32, c0 = blockIdx.x * 32;
    const int tx = threadIdx.x & 31, ty = threadIdx.x >> 5;
#pragma unroll
    for (int i = 0; i < 32; i += 8)
        tile[ty + i][tx] = src[(long)(r0 + ty + i) * 1024 + c0 + tx];
    __syncthreads();
#pragma unroll
    for (int i = 0; i < 32; i += 8)
        dst[(long)(c0 + ty + i) * 1024 + r0 + tx] = (__bf16)tile[tx][ty + i];
}

// ---------------------------------------------------------------------------
// Concatenate bq|bk|bv per layer into [L][3072]
// ---------------------------------------------------------------------------
__global__ __launch_bounds__(256) void qkv_bias_kernel(
    const float* __restrict__ bq, const float* __restrict__ bk,
    const float* __restrict__ bv, float* __restrict__ ob)
{
    int i = blockIdx.x * 256 + threadIdx.x;
    if (i >= LL * 3072) return;
    int l = i / 3072, j = i - l * 3072;
    float v = (j < 1024) ? bq[l * 1024 + j]
            : (j < 2048) ? bk[l * 1024 + j - 1024]
                         : bv[l * 1024 + j - 2048];
    ob[i] = v;
}

// ---------------------------------------------------------------------------
// Wave-per-row LayerNorm over H=1024: 4 rows per block, shuffle reductions.
// ---------------------------------------------------------------------------
__global__ __launch_bounds__(256) void ln_kernel(
    const __bf16* __restrict__ x, const float* __restrict__ g,
    const float* __restrict__ b, __bf16* __restrict__ outb)
{
    const int wv = threadIdx.x >> 6, lane = threadIdx.x & 63;
    const long row = blockIdx.x * 4 + wv;
    const __bf16* xr = x + row * HH_;
    float v[16];
    float s = 0.f, s2 = 0.f;
#pragma unroll
    for (int i = 0; i < 4; ++i) {
        bf16x4 vb = *(const bf16x4*)(xr + i * 256 + lane * 4);
#pragma unroll
        for (int j = 0; j < 4; ++j) {
            float f = (float)vb[j];
            v[i * 4 + j] = f; s += f; s2 += f * f;
        }
    }
#pragma unroll
    for (int m = 1; m < 64; m <<= 1) { s += __shfl_xor(s, m); s2 += __shfl_xor(s2, m); }
    float mu = s * (1.0f / 1024.0f);
    float var = s2 * (1.0f / 1024.0f) - mu * mu;
    float rstd = rsqrtf(var + 1e-5f);
    __bf16* orow = outb + row * HH_;
#pragma unroll
    for (int i = 0; i < 4; ++i) {
        float4 gv = *(const float4*)(g + i * 256 + lane * 4);
        float4 bv = *(const float4*)(b + i * 256 + lane * 4);
        bf16x4 ob = {(__bf16)((v[i*4+0] - mu) * rstd * gv.x + bv.x),
                     (__bf16)((v[i*4+1] - mu) * rstd * gv.y + bv.y),
                     (__bf16)((v[i*4+2] - mu) * rstd * gv.z + bv.z),
                     (__bf16)((v[i*4+3] - mu) * rstd * gv.w + bv.w)};
        *(bf16x4*)(orow + i * 256 + lane * 4) = ob;
    }
}

// ---------------------------------------------------------------------------
// Fused attention per batch z: scores (MFMA) -> sinkhorn (LDS, no-max) -> P@V.
// ---------------------------------------------------------------------------
__global__ __launch_bounds__(256) void attn_kernel(
    const __bf16* __restrict__ qkv, __bf16* __restrict__ att)
{
    const int z = blockIdx.x;
    __shared__ __bf16 sQ[64 * 32];
    __shared__ __bf16 sK[64 * 32];
    __shared__ float la[64 * 65];
    __shared__ float ps[4][64];
    __shared__ __bf16 sP[64 * 68];    // exp(P) bf16, padded
    __shared__ __bf16 sVT[64 * 68];   // V^T tile [n][c], padded

    const int t = threadIdx.x;
    const int wv = t >> 6, lane = t & 63;
    const int quad = lane >> 4, lrow = lane & 15;
    const int wm = (wv >> 1) * 32, wn = (wv & 1) * 32;

    // ---- phase 1: scores = Q K^T / 32 -> la ----
    {
        const int srow = t >> 2;
        const int skoff = (t & 3) * 8;
        __bf16* lq = sQ + wv * 512;
        __bf16* lk = sK + wv * 512;
        const __bf16* Q = qkv + (long)z * 64 * 3072;
        const __bf16* K = Q + 1024;

        f32x4 acc[2][2] = {};
        for (int k0 = 0; k0 < 1024; k0 += 32) {
            gld_lds16(Q + (long)srow * 3072 + k0 + skoff, lq);
            gld_lds16(K + (long)srow * 3072 + k0 + skoff, lk);
            __syncthreads();
            bf16x8 af[2], bfr[2];
#pragma unroll
            for (int i = 0; i < 2; ++i)
                af[i] = *(const bf16x8*)(sQ + (wm + i * 16 + lrow) * 32 + quad * 8);
#pragma unroll
            for (int j = 0; j < 2; ++j)
                bfr[j] = *(const bf16x8*)(sK + (wn + j * 16 + lrow) * 32 + quad * 8);
#pragma unroll
            for (int i = 0; i < 2; ++i)
#pragma unroll
                for (int j = 0; j < 2; ++j)
                    acc[i][j] = __builtin_amdgcn_mfma_f32_16x16x32_bf16(
                        af[i], bfr[j], acc[i][j], 0, 0, 0);
            __syncthreads();
        }
#pragma unroll
        for (int i = 0; i < 2; ++i)
#pragma unroll
            for (int p = 0; p < 4; ++p) {
                const int r = wm + i * 16 + quad * 4 + p;
#pragma unroll
                for (int j = 0; j < 2; ++j)
                    la[r * 65 + wn + j * 16 + lrow] = acc[i][j][p] * 0.03125f;
            }
        __syncthreads();
    }

    // ---- phase 2: sinkhorn, 50 iters, no max subtraction ----
    // |initial scores| <= ~2 (5 sigma), so exp is safe; after the first row
    // normalization all entries are <= 0.
    for (int it = 0; it < 50; ++it) {
        {   // row phase: row = lane, cols wv*16..+15
            float vr[16];
            float sum = 0.f;
#pragma unroll
            for (int i = 0; i < 16; ++i) vr[i] = la[lane * 65 + wv * 16 + i];
#pragma unroll
            for (int i = 0; i < 16; ++i) sum += __expf(vr[i]);
            ps[wv][lane] = sum;
            __syncthreads();
            float lse = __logf(ps[0][lane] + ps[1][lane] + ps[2][lane] + ps[3][lane]);
#pragma unroll
            for (int i = 0; i < 16; ++i) la[lane * 65 + wv * 16 + i] = vr[i] - lse;
            __syncthreads();
        }
        {   // col phase: col = lane, rows wv*16..+15
            float vr[16];
            float sum = 0.f;
#pragma unroll
            for (int i = 0; i < 16; ++i) vr[i] = la[(wv * 16 + i) * 65 + lane];
#pragma unroll
            for (int i = 0; i < 16; ++i) sum += __expf(vr[i]);
            ps[wv][lane] = sum;
            __syncthreads();
            float lse = __logf(ps[0][lane] + ps[1][lane] + ps[2][lane] + ps[3][lane]);
#pragma unroll
            for (int i = 0; i < 16; ++i) la[(wv * 16 + i) * 65 + lane] = vr[i] - lse;
            __syncthreads();
        }
    }

    // ---- phase 3: P = exp(la) -> bf16 sP ----
#pragma unroll
    for (int i = 0; i < 16; ++i) {
        int idx = t + i * 256;
        int r = idx >> 6, c = idx & 63;
        sP[r * 68 + c] = (__bf16)__expf(la[r * 65 + c]);
    }
    __syncthreads();

    // ---- phase 4: att = P @ V via MFMA, 16 column tiles of 64 ----
    const __bf16* V = qkv + (long)z * 64 * 3072 + 2048;
    const int vc = t >> 2;            // V row (agent c), 0..63
    const int vn = (t & 3) * 16;      // n offset within tile
    for (int tile = 0; tile < 16; ++tile) {
        bf16x8 v0 = *(const bf16x8*)(V + (long)vc * 3072 + tile * 64 + vn);
        bf16x8 v1 = *(const bf16x8*)(V + (long)vc * 3072 + tile * 64 + vn + 8);
#pragma unroll
        for (int j = 0; j < 8; ++j) sVT[(vn + j) * 68 + vc] = v0[j];
#pragma unroll
        for (int j = 0; j < 8; ++j) sVT[(vn + 8 + j) * 68 + vc] = v1[j];
        __syncthreads();

        f32x4 pacc[2][2] = {};
#pragma unroll
        for (int kb = 0; kb < 2; ++kb) {
            bf16x8 af[2], bfr[2];
#pragma unroll
            for (int i = 0; i < 2; ++i) {
                const __bf16* p = sP + (wm + i * 16 + lrow) * 68 + kb * 32 + quad * 8;
                bf16x4 lo = *(const bf16x4*)p;
                bf16x4 hi = *(const bf16x4*)(p + 4);
                af[i] = bf16x8{lo[0], lo[1], lo[2], lo[3], hi[0], hi[1], hi[2], hi[3]};
            }
#pragma unroll
            for (int j = 0; j < 2; ++j) {
                const __bf16* p = sVT + (wn + j * 16 + lrow) * 68 + kb * 32 + quad * 8;
                bf16x4 lo = *(const bf16x4*)p;
                bf16x4 hi = *(const bf16x4*)(p + 4);
                bfr[j] = bf16x8{lo[0], lo[1], lo[2], lo[3], hi[0], hi[1], hi[2], hi[3]};
            }
#pragma unroll
            for (int i = 0; i < 2; ++i)
#pragma unroll
                for (int j = 0; j < 2; ++j)
                    pacc[i][j] = __builtin_amdgcn_mfma_f32_16x16x32_bf16(
                        af[i], bfr[j], pacc[i][j], 0, 0, 0);
        }
#pragma unroll
        for (int i = 0; i < 2; ++i)
#pragma unroll
            for (int p = 0; p < 4; ++p) {
                const int r = wm + i * 16 + quad * 4 + p;
#pragma unroll
                for (int j = 0; j < 2; ++j) {
                    const int n = tile * 64 + wn + j * 16 + lrow;
                    att[((long)z * 64 + r) * HH_ + n] = (__bf16)pacc[i][j][p];
                }
            }
        __syncthreads();
    }
}

// ---------------------------------------------------------------------------
// Wave-per-row mix: 4 rows per block, shuffle reductions, no barriers.
// mix = 0.1*ns + 0.9*att; scaled = (mix+ab)*sf; bounded; h += bounded;
// if doLN: inter-LN -> h, then next pre-LN -> nsb_out.
// ---------------------------------------------------------------------------
__global__ __launch_bounds__(256) void mix_kernel(
    const __bf16* __restrict__ nsb_in, const __bf16* __restrict__ att,
    const float* __restrict__ ab, const float* __restrict__ sf,
    __bf16* __restrict__ h,
    const float* __restrict__ ig, const float* __restrict__ ib,
    const float* __restrict__ g2, const float* __restrict__ b2p, int doLN,
    __bf16* __restrict__ nsb_out)
{
    const int wv = threadIdx.x >> 6, lane = threadIdx.x & 63;
    const long row = blockIdx.x * 4 + wv;
    const int a = (int)(row & 63);
    const float sfa = sf[a];

    const __bf16* nr = nsb_in + row * HH_;
    const __bf16* ar = att + row * HH_;
    const float* abr = ab + (long)a * HH_;

    float sc[16];
    float nrm2 = 0.f;
#pragma unroll
    for (int i = 0; i < 4; ++i) {
        bf16x4 nv = *(const bf16x4*)(nr + i * 256 + lane * 4);
        bf16x4 av = *(const bf16x4*)(ar + i * 256 + lane * 4);
        float4 a4 = *(const float4*)(abr + i * 256 + lane * 4);
        float v0 = (0.1f * (float)nv[0] + 0.9f * (float)av[0] + a4.x) * sfa;
        float v1 = (0.1f * (float)nv[1] + 0.9f * (float)av[1] + a4.y) * sfa;
        float v2 = (0.1f * (float)nv[2] + 0.9f * (float)av[2] + a4.z) * sfa;
        float v3 = (0.1f * (float)nv[3] + 0.9f * (float)av[3] + a4.w) * sfa;
        sc[i*4+0] = v0; sc[i*4+1] = v1; sc[i*4+2] = v2; sc[i*4+3] = v3;
        nrm2 += v0 * v0 + v1 * v1 + v2 * v2 + v3 * v3;
    }
#pragma unroll
    for (int m = 1; m < 64; m <<= 1) nrm2 += __shfl_xor(nrm2, m);
    float norm = sqrtf(nrm2);
    float inv = norm > 1.0f ? 1.0f / norm : 1.0f;

    __bf16* hr = h + row * HH_;
    float hn[16];
    float s = 0.f, s2 = 0.f;
#pragma unroll
    for (int i = 0; i < 4; ++i) {
        bf16x4 hv = *(const bf16x4*)(hr + i * 256 + lane * 4);
#pragma unroll
        for (int j = 0; j < 4; ++j) {
            float f = (float)hv[j] + sc[i * 4 + j] * inv;
            hn[i * 4 + j] = f; s += f; s2 += f * f;
        }
    }
    if (!doLN) {
#pragma unroll
        for (int i = 0; i < 4; ++i) {
            bf16x4 ob = {(__bf16)hn[i*4+0], (__bf16)hn[i*4+1],
                         (__bf16)hn[i*4+2], (__bf16)hn[i*4+3]};
            *(bf16x4*)(hr + i * 256 + lane * 4) = ob;
        }
        return;
    }
#pragma unroll
    for (int m = 1; m < 64; m <<= 1) { s += __shfl_xor(s, m); s2 += __shfl_xor(s2, m); }
    float mu = s * (1.0f / 1024.0f);
    float var = s2 * (1.0f / 1024.0f) - mu * mu;
    float rstd = rsqrtf(var + 1e-5f);
    float s_1 = 0.f, s2_1 = 0.f;
#pragma unroll
    for (int i = 0; i < 4; ++i) {
        float4 gv = *(const float4*)(ig + i * 256 + lane * 4);
        float4 bv = *(const float4*)(ib + i * 256 + lane * 4);
        float f0 = (hn[i*4+0] - mu) * rstd * gv.x + bv.x;
        float f1 = (hn[i*4+1] - mu) * rstd * gv.y + bv.y;
        float f2 = (hn[i*4+2] - mu) * rstd * gv.z + bv.z;
        float f3 = (hn[i*4+3] - mu) * rstd * gv.w + bv.w;
        hn[i*4+0] = f0; hn[i*4+1] = f1; hn[i*4+2] = f2; hn[i*4+3] = f3;
        s_1 += f0 + f1 + f2 + f3;
        s2_1 += f0 * f0 + f1 * f1 + f2 * f2 + f3 * f3;
        bf16x4 ob = {(__bf16)f0, (__bf16)f1, (__bf16)f2, (__bf16)f3};
        *(bf16x4*)(hr + i * 256 + lane * 4) = ob;
    }
#pragma unroll
    for (int m = 1; m < 64; m <<= 1) { s_1 += __shfl_xor(s_1, m); s2_1 += __shfl_xor(s2_1, m); }
    mu = s_1 * (1.0f / 1024.0f);
    var = s2_1 * (1.0f / 1024.0f) - mu * mu;
    rstd = rsqrtf(var + 1e-5f);
    __bf16* nor = nsb_out + row * HH_;
#pragma unroll
    for (int i = 0; i < 4; ++i) {
        float4 gv = *(const float4*)(g2 + i * 256 + lane * 4);
        float4 bv = *(const float4*)(b2p + i * 256 + lane * 4);
        bf16x4 ob = {(__bf16)((hn[i*4+0] - mu) * rstd * gv.x + bv.x),
                     (__bf16)((hn[i*4+1] - mu) * rstd * gv.y + bv.y),
                     (__bf16)((hn[i*4+2] - mu) * rstd * gv.z + bv.z),
                     (__bf16)((hn[i*4+3] - mu) * rstd * gv.w + bv.w)};
        *(bf16x4*)(nor + i * 256 + lane * 4) = ob;
    }
}

// ---------------------------------------------------------------------------
extern "C" void kernel_launch(void* const* d_in, const int* in_sizes, int n_in,
                              void* d_out, int out_size, void* d_ws, size_t ws_size,
                              hipStream_t stream)
{
    const float* agent_states = (const float*)d_in[0];
    const float* Win   = (const float*)d_in[1];
    const float* bin_  = (const float*)d_in[2];
    const float* ln_g  = (const float*)d_in[3];
    const float* ln_b  = (const float*)d_in[4];
    const float* Wq    = (const float*)d_in[5];
    const float* bq    = (const float*)d_in[6];
    const float* Wk    = (const float*)d_in[7];
    const float* bk    = (const float*)d_in[8];
    const float* Wv    = (const float*)d_in[9];
    const float* bv    = (const float*)d_in[10];
    const float* ab    = (const float*)d_in[11];
    const float* sf    = (const float*)d_in[12];
    const float* ilg   = (const float*)d_in[13];
    const float* ilb   = (const float*)d_in[14];
    const float* W1    = (const float*)d_in[15];
    const float* b1    = (const float*)d_in[16];
    const float* W2    = (const float*)d_in[17];
    const float* b2    = (const float*)d_in[18];
    float* out = (float*)d_out;

    // ---- workspace layout ----
    float* qbias = (float*)d_ws;                 // 16384 floats (9216 used)
    __bf16* base = (__bf16*)(qbias + 16384);
    __bf16* nsb   = base;                        // HN
    __bf16* h     = nsb + HN;                    // HN
    __bf16* att   = h + HN;                      // HN
    __bf16* qkvb  = att + HN;                    // 3*HN = 50,331,648
    __bf16* Wqkvt = qkvb + 3 * HN;               // 9,437,184
    // pre-loop overlays (att unused until layer 0 attention):
    __bf16* asb  = att;                          // 8,388,608
    __bf16* Wint = att + 8388608;                // 524,288
    // post-loop overlays (qkvb dead after last attention):
    __bf16* W1t = qkvb;                          // 33,554,432
    __bf16* W2t = qkvb + 33554432;               // 8,388,608
    __bf16* yb  = qkvb + 41943040;               // 8,388,608

    // ---- prep: casts / packs ----
    cast_kernel<<<8192, 256, 0, stream>>>(agent_states, asb);
    transpose_cast_kernel<<<dim3(32, 16, 1), 256, 0, stream>>>(Win, Wint, 512, 1024, 0, 0);
    transpose_qkv_kernel<<<dim3(32, 32, 9), 256, 0, stream>>>(Wq, Wk, Wv, Wqkvt);
    qkv_bias_kernel<<<36, 256, 0, stream>>>(bq, bk, bv, qbias);

    // ---- input projection: h(bf16) = asb @ Win^T + bin ----
    mfma_gemm<0, 1, 0><<<dim3(8, 128, 1), 256, 0, stream>>>(
        asb, Wint, bin_, nullptr, h, ROWS, HH_, DIN, DIN, DIN, HH_, 0, 0, 0, 0);
    ln_kernel<<<ROWS / 4, 256, 0, stream>>>(h, ln_g, ln_b, nsb);

    for (int i = 0; i < LL; ++i) {
        mfma_gemm<0, 1, 1><<<dim3(24, 128, 1), 256, 0, stream>>>(
            nsb, Wqkvt + (long)i * 3145728, qbias + i * 3072, nullptr, qkvb,
            ROWS, 3072, HH_, HH_, HH_, 3072, 0, 0, 0, 0);
        attn_kernel<<<BB, 256, 0, stream>>>(qkvb, att);
        const int last = (i == LL - 1);
        mix_kernel<<<ROWS / 4, 256, 0, stream>>>(
            nsb, att, ab + (long)i * AA * HH_, sf + i * AA, h,
            ilg + (last ? 0 : i) * HH_, ilb + (last ? 0 : i) * HH_,
            ln_g + (last ? 0 : (i + 1)) * HH_, ln_b + (last ? 0 : (i + 1)) * HH_,
            last ? 0 : 1, nsb);
    }

    // ---- heads ----
    transpose_cast_kernel<<<dim3(16, 32, 64), 256, 0, stream>>>(W1, W1t, 1024, 512,
                                                                524288, 524288);
    transpose_cast_kernel<<<dim3(8, 16, 64), 256, 0, stream>>>(W2, W2t, 512, 256,
                                                               131072, 131072);
    mfma_gemm<1, 1, 0><<<dim3(4, 2, 64), 256, 0, stream>>>(
        h, W1t, b1, nullptr, yb, BB, HHALF, HH_,
        AA * HH_, HH_, AA * HHALF, HH_, (long)HHALF * HH_, HHALF, HHALF);
    mfma_gemm<0, 0, 0><<<dim3(2, 2, 64), 256, 0, stream>>>(
        yb, W2t, b2, out, nullptr, BB, OUTD, HHALF,
        AA * HHALF, HHALF, AA * OUTD, HHALF, (long)OUTD * HHALF, OUTD, OUTD);
}